// Round 8
// baseline (984.662 us; speedup 1.0000x reference)
//
#include <hip/hip_runtime.h>

// Problem constants
#define BSZ  128
#define TT   50
#define CIN  2312
#define HID  300
#define NOUT 10
#define KS   5
#define T1   51          // (TT+5) - KS + 1
#define T2   52          // (T1+5) - KS + 1

#define NC32 73          // ceil(CIN/32) K-chunks of 32
#define KFRAG_U 20480    // u16 units per (ow,chunk): 5k * 4nt * 2h * 512

typedef unsigned int u32;
typedef unsigned short u16;
typedef __attribute__((ext_vector_type(8))) short s16x8;   // 8 bf16 (4 VGPRs)
typedef __attribute__((ext_vector_type(4))) float f32x4;   // MFMA C/D

// exp(-k^2/8) constants, k=1..4 (fp32)
#define EK1f 0.88249690258459546f
#define EK2f 0.60653065971263342f
#define EK3f 0.32465246735834974f
#define EK4f 0.13533528323661270f

static __device__ __forceinline__ u16 bfhi(float x) {
  u32 u = __float_as_uint(x);
  return (u16)((u + 0x7fffu + ((u >> 16) & 1u)) >> 16);   // RNE bf16
}
static __device__ __forceinline__ float bf2f(u16 h) {
  return __uint_as_float(((u32)h) << 16);
}

// ===========================================================================
// prep: synthesize gauss kernel once, split into bf16 hi/lo, in exact MFMA
// B-fragment order: [ow][chunk][k][nt][h][lane][8] (frag = 64 lanes x 16 B).
// ===========================================================================
__global__ __launch_bounds__(256) void snn_prepm(
    const float* __restrict__ W1, const float* __restrict__ P1,
    u16* __restrict__ K1bf)
{
  const int c  = blockIdx.x;          // 0..72
  const int ow = blockIdx.y;          // 0..4
  const int tid = threadIdx.x;
  const int nt = tid >> 6, ll = tid & 63;
  const int g = ll >> 4, lr = ll & 15;
  const int o  = ow * 64 + nt * 16 + lr;
  const int ib = c * 32 + g * 8;

  s16x8 hv[5], lv[5];
#pragma unroll
  for (int k = 0; k < 5; ++k)
#pragma unroll
    for (int j = 0; j < 8; ++j) { hv[k][j] = 0; lv[k][j] = 0; }

  if (o < HID) {
    const float* wrow = W1 + (size_t)o * CIN;
    const float* prow = P1 + (size_t)o * CIN;
#pragma unroll
    for (int j = 0; j < 8; ++j) {
      const int i = ib + j;
      if (i < CIN) {
        const float w1 = wrow[i], p1 = prow[i];
        const float cc = p1 + 2.0f;
        const float E0 = __expf(-0.125f * cc * cc);
        const float U  = __expf(0.25f * cc);
        const float u2 = U * U;
        const float e0 = E0;
        const float e1 = E0 * U * EK1f;
        const float e2 = E0 * u2 * EK2f;
        const float e3 = E0 * (u2 * U) * EK3f;
        const float e4 = E0 * (u2 * u2) * EK4f;
        const float inv = 1.0f / (((((e0 + e1) + e2) + e3) + e4) + 1e-7f);
        const float vk[5] = { w1 * (e0 * inv), w1 * (e1 * inv),
                              w1 * (e2 * inv), w1 * (e3 * inv),
                              w1 * (e4 * inv) };
#pragma unroll
        for (int k = 0; k < 5; ++k) {
          const u16 h = bfhi(vk[k]);
          const u16 lo = bfhi(vk[k] - bf2f(h));
          hv[k][j] = (short)h; lv[k][j] = (short)lo;
        }
      }
    }
  }
  u16* base = K1bf + ((size_t)ow * NC32 + c) * KFRAG_U + nt * 1024 + ll * 8;
#pragma unroll
  for (int k = 0; k < 5; ++k) {
    *(s16x8*)(base + k * 4096)       = hv[k];
    *(s16x8*)(base + k * 4096 + 512) = lv[k];
  }
}

// ===========================================================================
// Layer-1 split-K MFMA kernel (round-5 proven structure, K halved per block).
// 1280 blocks: (s, ow, b) with s = K-half. Each block: C[64t][64o] partial
// over chunks [c_lo, c_hi), mfma_f32_16x16x32_bf16, 3-term bf16 split,
// per-chunk fp64 promotion, result stored as fp32 partial to pbuf.
// Waves 2x2 (wave (wr,wc): rows 32wr..+31, cols 32wc..+31; 3 MFMA/ds_read).
// A: double-buffered LDS (parity = chunk&1), natural stride-80B banking.
// B: 20 frags/wave in regs, rolling per-tap reload after last use.
// XCD-chunked rank: XCD g owns 80 (ow,b) pairs x both s-halves.
// __launch_bounds__(256,4): VGPR<=128 -> 4 blocks/CU resident (16 waves/CU),
// double round-5's grid-limited 2.5 -> latency finally hidden by TLP.
// LDS: 2 x (hi 2720 + lo 2720) u16 = 21760 B.
// ===========================================================================
__global__ __launch_bounds__(256, 4) void snn_l1s(
    const float* __restrict__ data, const u16* __restrict__ K1bf,
    float* __restrict__ pbuf)
{
  __shared__ __align__(16) double dsm[2720];   // 21760 B
  u16* A16 = (u16*)dsm;

  const int tid = threadIdx.x;
  const int bid = blockIdx.x;
  const int g  = bid & 7;            // XCD
  const int r  = bid >> 3;           // 0..159
  const int s  = r & 1;              // K-half
  const int u  = r >> 1;             // 0..79
  const int x  = g * 80 + u;         // pair rank 0..639 (ow-major per XCD)
  const int ow = x >> 7;             // 0..4
  const int b  = x & 127;

  const int c_lo = s ? 37 : 0;
  const int c_hi = s ? 73 : 37;

  const int w  = tid >> 6, l = tid & 63;
  const int lr = l & 15, lg = l >> 4;
  const int wr = w >> 1, wc = w & 1;
  const int abase_u = (32 * wr + lr) * 40 + lg * 8;   // A-frag base (u16)

  const float* dbase = data + (size_t)b * (TT * CIN);
  const u16* kbn = K1bf + (size_t)ow * NC32 * KFRAG_U + l * 8;
  const int ntg0 = wc * 2, ntg1 = wc * 2 + 1;

  // A staging thread mapping: slot s1 (0..63), i-group j4 (0..3)
  const int s1 = tid >> 2;
  const int j4 = tid & 3;
  const int tp = s1 - 5;
  const bool avld = (tp >= 0) && (tp < TT);
  const float* aptr = dbase + (size_t)(avld ? tp : 0) * CIN + j4 * 8;

  // zero pad rows 64..67 (tap overhang) in both buffers, hi+lo
  if (tid < 80) {
    s16x8 z;
#pragma unroll
    for (int j = 0; j < 8; ++j) z[j] = 0;
    const int rr = tid / 20, off = (tid % 20) * 8;
    *(s16x8*)(A16 + rr * 2720 + 2560 + off) = z;
  }

#define LOADA(CC)                                                             \
  {                                                                           \
    const bool iv_ = avld && (((CC) < 72) || (j4 == 0));                      \
    const float* pp_ = aptr + (size_t)(CC) * 32;                              \
    ra0 = iv_ ? *(const float4*)(pp_)     : make_float4(0.f, 0.f, 0.f, 0.f);  \
    ra1 = iv_ ? *(const float4*)(pp_ + 4) : make_float4(0.f, 0.f, 0.f, 0.f);  \
  }

#define STAGE_A(CC)                                                           \
  {                                                                           \
    const float f_[8] = { ra0.x, ra0.y, ra0.z, ra0.w,                         \
                          ra1.x, ra1.y, ra1.z, ra1.w };                       \
    s16x8 hv_, lv_;                                                           \
    _Pragma("unroll")                                                         \
    for (int j = 0; j < 8; ++j) {                                             \
      const u16 h_ = bfhi(f_[j]);                                             \
      hv_[j] = (short)h_;                                                     \
      lv_[j] = (short)bfhi(f_[j] - bf2f(h_));                                 \
    }                                                                         \
    u16* bn_ = A16 + ((CC) & 1) * 5440;                                       \
    const int woff_ = s1 * 40 + j4 * 8;                                       \
    *(s16x8*)(bn_ + woff_) = hv_;                                             \
    *(s16x8*)(bn_ + 2720 + woff_) = lv_;                                      \
  }

  // ---- B frag registers: 20 per wave, rolling per-tap reload ----
  s16x8 bh[5][2], bl[5][2];
#pragma unroll
  for (int k = 0; k < 5; ++k) {
    const u16* cb_ = kbn + (size_t)c_lo * KFRAG_U + k * 4096;
    bh[k][0] = *(const s16x8*)(cb_ + ntg0 * 1024);
    bh[k][1] = *(const s16x8*)(cb_ + ntg1 * 1024);
    bl[k][0] = *(const s16x8*)(cb_ + ntg0 * 1024 + 512);
    bl[k][1] = *(const s16x8*)(cb_ + ntg1 * 1024 + 512);
  }

  f32x4 accf[2][2];
  double accd[2][2][4];
#pragma unroll
  for (int m = 0; m < 2; ++m)
#pragma unroll
    for (int n = 0; n < 2; ++n)
#pragma unroll
      for (int q = 0; q < 4; ++q) { accf[m][n][q] = 0.f; accd[m][n][q] = 0.0; }

  // ---- prologue: stage chunk c_lo; prefetch A regs <- c_lo+1 ----
  float4 ra0, ra1;
  LOADA(c_lo);
  STAGE_A(c_lo);
  LOADA(c_lo + 1);
  __syncthreads();

  // ---- main loop: per-chunk barrier (round-5 proven schedule) ----
  for (int c = c_lo; c < c_hi; ++c) {
    // stage next chunk into the other buffer; prefetch A regs <- c+2
    if (c + 1 < c_hi) {
      STAGE_A(c + 1);
      if (c + 2 < c_hi) LOADA(c + 2);
    }

    // compute chunk c: 5 taps x (2m x 2n) x 3 terms; rolling B reload <- c+1
    {
      const u16* bc_ = A16 + (c & 1) * 5440;
      const int rc = c + 1;
#pragma unroll
      for (int k = 0; k < 5; ++k) {
        const s16x8 ah0 = *(const s16x8*)(bc_ + abase_u + k * 40);
        const s16x8 al0 = *(const s16x8*)(bc_ + 2720 + abase_u + k * 40);
        const s16x8 ah1 = *(const s16x8*)(bc_ + abase_u + (16 + k) * 40);
        const s16x8 al1 = *(const s16x8*)(bc_ + 2720 + abase_u + (16 + k) * 40);

        accf[0][0] = __builtin_amdgcn_mfma_f32_16x16x32_bf16(ah0, bh[k][0], accf[0][0], 0, 0, 0);
        accf[0][0] = __builtin_amdgcn_mfma_f32_16x16x32_bf16(al0, bh[k][0], accf[0][0], 0, 0, 0);
        accf[0][0] = __builtin_amdgcn_mfma_f32_16x16x32_bf16(ah0, bl[k][0], accf[0][0], 0, 0, 0);

        accf[0][1] = __builtin_amdgcn_mfma_f32_16x16x32_bf16(ah0, bh[k][1], accf[0][1], 0, 0, 0);
        accf[0][1] = __builtin_amdgcn_mfma_f32_16x16x32_bf16(al0, bh[k][1], accf[0][1], 0, 0, 0);
        accf[0][1] = __builtin_amdgcn_mfma_f32_16x16x32_bf16(ah0, bl[k][1], accf[0][1], 0, 0, 0);

        accf[1][0] = __builtin_amdgcn_mfma_f32_16x16x32_bf16(ah1, bh[k][0], accf[1][0], 0, 0, 0);
        accf[1][0] = __builtin_amdgcn_mfma_f32_16x16x32_bf16(al1, bh[k][0], accf[1][0], 0, 0, 0);
        accf[1][0] = __builtin_amdgcn_mfma_f32_16x16x32_bf16(ah1, bl[k][0], accf[1][0], 0, 0, 0);

        accf[1][1] = __builtin_amdgcn_mfma_f32_16x16x32_bf16(ah1, bh[k][1], accf[1][1], 0, 0, 0);
        accf[1][1] = __builtin_amdgcn_mfma_f32_16x16x32_bf16(al1, bh[k][1], accf[1][1], 0, 0, 0);
        accf[1][1] = __builtin_amdgcn_mfma_f32_16x16x32_bf16(ah1, bl[k][1], accf[1][1], 0, 0, 0);

        if (rc < c_hi) {
          const u16* cb_ = kbn + (size_t)rc * KFRAG_U + k * 4096;
          bh[k][0] = *(const s16x8*)(cb_ + ntg0 * 1024);
          bh[k][1] = *(const s16x8*)(cb_ + ntg1 * 1024);
          bl[k][0] = *(const s16x8*)(cb_ + ntg0 * 1024 + 512);
          bl[k][1] = *(const s16x8*)(cb_ + ntg1 * 1024 + 512);
        }
      }
    }

    // promote chunk partial into fp64
#pragma unroll
    for (int m = 0; m < 2; ++m)
#pragma unroll
      for (int n = 0; n < 2; ++n)
#pragma unroll
        for (int q = 0; q < 4; ++q) {
          accd[m][n][q] += (double)accf[m][n][q];
          accf[m][n][q] = 0.f;
        }
    __syncthreads();
  }
#undef LOADA
#undef STAGE_A

  // ---- store fp32 partial tile [51][64] ----
  // C/D layout: col = lane&15, row = (lane>>4)*4 + reg
  float* pb = pbuf + (((size_t)s * 5 + ow) * 128 + b) * 3264;
#pragma unroll
  for (int m = 0; m < 2; ++m)
#pragma unroll
    for (int n = 0; n < 2; ++n)
#pragma unroll
      for (int q = 0; q < 4; ++q) {
        const int t = 32 * wr + 16 * m + lg * 4 + q;
        if (t < T1) pb[t * 64 + 32 * wc + 16 * n + lr] = (float)accd[m][n][q];
      }
}

// ===========================================================================
// Fused layer-2: reduce split-K partials + LIF1 + ballot + conv2 + LIF2.
// 128 blocks (one per batch). smem floats: [0,15000) K2s [o][k][i],
// [15000,15510) lbits u32, [15510,16030) y2s [t2][o].
// ===========================================================================
__global__ __launch_bounds__(256) void snn_l2m(
    const float* __restrict__ pbuf, const float* __restrict__ b1v,
    const float* __restrict__ W2, const float* __restrict__ P2,
    const float* __restrict__ b2, float* __restrict__ out)
{
  __shared__ float smem[16030];
  const int b = blockIdx.x, tid = threadIdx.x;
  float* K2s = smem;
  u32* lbits = (u32*)(smem + 15000);
  float* y2s = smem + 15510;

  // ---- K2 synthesis (all 256 threads) ----
  for (int idx = tid; idx < NOUT * HID; idx += 256) {
    const int o = idx / HID, i = idx % HID;
    const float w = W2[idx], p = P2[idx];
    const float c = p + 2.0f;
    float e[KS], ssum = 0.f;
#pragma unroll
    for (int k = 0; k < KS; ++k) {
      const float d = ((float)k - c) * 0.5f;
      e[k] = __expf(-0.5f * d * d);
      ssum += e[k];
    }
    const float denom = ssum + 1e-7f;
#pragma unroll
    for (int k = 0; k < KS; ++k)
      K2s[(o * KS + k) * HID + i] = w * (e[k] / denom);
  }

  // ---- fused reduce + LIF1 + ballot: wave w handles ow = w (+4) ----
  {
    const int w = tid >> 6, l = tid & 63;
    for (int ow = w; ow < 5; ow += 4) {
      const int o = ow * 64 + l;
      const bool valid = o < HID;
      const double bias = valid ? (double)b1v[o] : 0.0;
      const float* p0 = pbuf + (((size_t)0 * 5 + ow) * 128 + b) * 3264 + l;
      const float* p1 = pbuf + (((size_t)1 * 5 + ow) * 128 + b) * 3264 + l;
      double mem = 0.0;
      for (int t = 0; t < T1; ++t) {
        const double x = (double)p0[t * 64] + (double)p1[t * 64] + bias;
        const double reset = (mem > 1.0) ? 1.0 : 0.0;
        mem = __dsub_rn(__dadd_rn(__dmul_rn(0.9, mem), x), reset);
        const unsigned long long mk = __ballot(valid && (mem > 1.0));
        if (l == 0)  lbits[t * 10 + 2 * ow]     = (u32)mk;
        if (l == 32) lbits[t * 10 + 2 * ow + 1] = (u32)(mk >> 32);
      }
    }
  }
  __syncthreads();                    // fences K2s + lbits

  // ---- conv2 ----
  for (int task = tid; task < T2 * NOUT; task += 256) {
    const int t2 = task / NOUT, o = task % NOUT;
    float acc = b2[o];
#pragma unroll
    for (int k = 0; k < KS; ++k) {
      const int tp = t2 + k - KS;
      if (tp < 0 || tp >= T1) continue;
      const float* kr = K2s + (o * KS + k) * HID;
      const u32* br = lbits + tp * 10;
      for (int i = 0; i < HID; ++i)
        acc = fmaf((float)((br[i >> 5] >> (i & 31)) & 1u), kr[i], acc);
    }
    y2s[task] = acc;
  }
  __syncthreads();

  // ---- LIF2 + output ----
  if (tid < NOUT) {
    float mem = 0.f;
    for (int t = 0; t < T2; ++t) {
      const float x = y2s[t * NOUT + tid];
      const float reset = (mem > 1.0f) ? 1.0f : 0.0f;
      mem = __fsub_rn(__fadd_rn(__fmul_rn(0.9f, mem), x), reset);
      out[(size_t)t * (BSZ * NOUT) + b * NOUT + tid] = (mem > 1.0f) ? 1.0f : 0.0f;
      out[(size_t)T2 * BSZ * NOUT + (size_t)t * (BSZ * NOUT) + b * NOUT + tid] = mem;
    }
  }
}

// ===========================================================================
// Fallback 1: round-5 proven l1m (full-K per block, gbits output) — used
// when workspace fits K1bf but not the split-K partial buffer.
// ===========================================================================
__global__ __launch_bounds__(256, 2) void snn_l1m(
    const float* __restrict__ data, const u16* __restrict__ K1bf,
    const float* __restrict__ b1v, u32* __restrict__ gbits)
{
  __shared__ double dsm[3264];         // 26112 B
  u16* A16 = (u16*)dsm;

  const int tid = threadIdx.x;
  const int bid = blockIdx.x;
  const int rnk = (bid & 7) * 80 + (bid >> 3);
  const int ow = rnk >> 7;
  const int b  = rnk & 127;

  const int w  = tid >> 6, l = tid & 63;
  const int lr = l & 15, lg = l >> 4;
  const int wr = w >> 1, wc = w & 1;
  const int abase_u = (32 * wr + lr) * 40 + lg * 8;

  const float* dbase = data + (size_t)b * (TT * CIN);
  const u16* kbn = K1bf + (size_t)ow * NC32 * KFRAG_U + l * 8;
  const int ntg0 = wc * 2, ntg1 = wc * 2 + 1;

  const int s1 = tid >> 2;
  const int j4 = tid & 3;
  const int tp = s1 - 5;
  const bool avld = (tp >= 0) && (tp < TT);
  const float* aptr = dbase + (size_t)(avld ? tp : 0) * CIN + j4 * 8;

  if (tid < 80) {
    s16x8 z;
#pragma unroll
    for (int j = 0; j < 8; ++j) z[j] = 0;
    const int rr = tid / 20, off = (tid % 20) * 8;
    *(s16x8*)(A16 + rr * 2720 + 2560 + off) = z;
  }

#define LOADA(CC)                                                             \
  {                                                                           \
    const bool iv_ = avld && (((CC) < 72) || (j4 == 0));                      \
    const float* pp_ = aptr + (size_t)(CC) * 32;                              \
    ra0 = iv_ ? *(const float4*)(pp_)     : make_float4(0.f, 0.f, 0.f, 0.f);  \
    ra1 = iv_ ? *(const float4*)(pp_ + 4) : make_float4(0.f, 0.f, 0.f, 0.f);  \
  }

#define STAGE_A(CC)                                                           \
  {                                                                           \
    const float f_[8] = { ra0.x, ra0.y, ra0.z, ra0.w,                         \
                          ra1.x, ra1.y, ra1.z, ra1.w };                       \
    s16x8 hv_, lv_;                                                           \
    _Pragma("unroll")                                                         \
    for (int j = 0; j < 8; ++j) {                                             \
      const u16 h_ = bfhi(f_[j]);                                             \
      hv_[j] = (short)h_;                                                     \
      lv_[j] = (short)bfhi(f_[j] - bf2f(h_));                                 \
    }                                                                         \
    u16* bn_ = A16 + ((CC) & 1) * 5440;                                       \
    const int woff_ = s1 * 40 + j4 * 8;                                       \
    *(s16x8*)(bn_ + woff_) = hv_;                                             \
    *(s16x8*)(bn_ + 2720 + woff_) = lv_;                                      \
  }

  s16x8 bh[5][2], bl[5][2];
#pragma unroll
  for (int k = 0; k < 5; ++k) {
    const u16* cb_ = kbn + k * 4096;
    bh[k][0] = *(const s16x8*)(cb_ + ntg0 * 1024);
    bh[k][1] = *(const s16x8*)(cb_ + ntg1 * 1024);
    bl[k][0] = *(const s16x8*)(cb_ + ntg0 * 1024 + 512);
    bl[k][1] = *(const s16x8*)(cb_ + ntg1 * 1024 + 512);
  }

  f32x4 accf[2][2];
  double accd[2][2][4];
#pragma unroll
  for (int m = 0; m < 2; ++m)
#pragma unroll
    for (int n = 0; n < 2; ++n)
#pragma unroll
      for (int q = 0; q < 4; ++q) { accf[m][n][q] = 0.f; accd[m][n][q] = 0.0; }

  float4 ra0, ra1;
  LOADA(0);
  STAGE_A(0);
  LOADA(1);
  __syncthreads();

  for (int c = 0; c < NC32; ++c) {
    if (c + 1 < NC32) {
      STAGE_A(c + 1);
      if (c + 2 < NC32) LOADA(c + 2);
    }
    {
      const u16* bc_ = A16 + (c & 1) * 5440;
      const int rc = c + 1;
#pragma unroll
      for (int k = 0; k < 5; ++k) {
        const s16x8 ah0 = *(const s16x8*)(bc_ + abase_u + k * 40);
        const s16x8 al0 = *(const s16x8*)(bc_ + 2720 + abase_u + k * 40);
        const s16x8 ah1 = *(const s16x8*)(bc_ + abase_u + (16 + k) * 40);
        const s16x8 al1 = *(const s16x8*)(bc_ + 2720 + abase_u + (16 + k) * 40);

        accf[0][0] = __builtin_amdgcn_mfma_f32_16x16x32_bf16(ah0, bh[k][0], accf[0][0], 0, 0, 0);
        accf[0][0] = __builtin_amdgcn_mfma_f32_16x16x32_bf16(al0, bh[k][0], accf[0][0], 0, 0, 0);
        accf[0][0] = __builtin_amdgcn_mfma_f32_16x16x32_bf16(ah0, bl[k][0], accf[0][0], 0, 0, 0);
        accf[0][1] = __builtin_amdgcn_mfma_f32_16x16x32_bf16(ah0, bh[k][1], accf[0][1], 0, 0, 0);
        accf[0][1] = __builtin_amdgcn_mfma_f32_16x16x32_bf16(al0, bh[k][1], accf[0][1], 0, 0, 0);
        accf[0][1] = __builtin_amdgcn_mfma_f32_16x16x32_bf16(ah0, bl[k][1], accf[0][1], 0, 0, 0);
        accf[1][0] = __builtin_amdgcn_mfma_f32_16x16x32_bf16(ah1, bh[k][0], accf[1][0], 0, 0, 0);
        accf[1][0] = __builtin_amdgcn_mfma_f32_16x16x32_bf16(al1, bh[k][0], accf[1][0], 0, 0, 0);
        accf[1][0] = __builtin_amdgcn_mfma_f32_16x16x32_bf16(ah1, bl[k][0], accf[1][0], 0, 0, 0);
        accf[1][1] = __builtin_amdgcn_mfma_f32_16x16x32_bf16(ah1, bh[k][1], accf[1][1], 0, 0, 0);
        accf[1][1] = __builtin_amdgcn_mfma_f32_16x16x32_bf16(al1, bh[k][1], accf[1][1], 0, 0, 0);
        accf[1][1] = __builtin_amdgcn_mfma_f32_16x16x32_bf16(ah1, bl[k][1], accf[1][1], 0, 0, 0);

        if (rc < NC32) {
          const u16* cb_ = kbn + (size_t)rc * KFRAG_U + k * 4096;
          bh[k][0] = *(const s16x8*)(cb_ + ntg0 * 1024);
          bh[k][1] = *(const s16x8*)(cb_ + ntg1 * 1024);
          bl[k][0] = *(const s16x8*)(cb_ + ntg0 * 1024 + 512);
          bl[k][1] = *(const s16x8*)(cb_ + ntg1 * 1024 + 512);
        }
      }
    }
#pragma unroll
    for (int m = 0; m < 2; ++m)
#pragma unroll
      for (int n = 0; n < 2; ++n)
#pragma unroll
        for (int q = 0; q < 4; ++q) {
          accd[m][n][q] += (double)accf[m][n][q];
          accf[m][n][q] = 0.f;
        }
    __syncthreads();
  }
#undef LOADA
#undef STAGE_A

  double* y1s = dsm;
#pragma unroll
  for (int m = 0; m < 2; ++m)
#pragma unroll
    for (int n = 0; n < 2; ++n)
#pragma unroll
      for (int q = 0; q < 4; ++q) {
        const int t = 32 * wr + 16 * m + lg * 4 + q;
        if (t < T1) y1s[t * 64 + 32 * wc + 16 * n + lr] = accd[m][n][q];
      }
  __syncthreads();

  if (tid < 64) {
    const int o = ow * 64 + tid;
    const bool valid = o < HID;
    const double bias = valid ? (double)b1v[o] : 0.0;
    u32* bits = gbits + (size_t)b * 510;
    double mem = 0.0;
    for (int t = 0; t < T1; ++t) {
      const double x = y1s[t * 64 + tid] + bias;
      const double reset = (mem > 1.0) ? 1.0 : 0.0;
      mem = __dsub_rn(__dadd_rn(__dmul_rn(0.9, mem), x), reset);
      const unsigned long long mk = __ballot(valid && (mem > 1.0));
      if (tid == 0)  bits[t * 10 + 2 * ow]     = (u32)mk;
      if (tid == 32) bits[t * 10 + 2 * ow + 1] = (u32)(mk >> 32);
    }
  }
}

// ===========================================================================
// Fallback 2: fp32 layer-1 (gauss in-kernel) — round-1/2 proven path.
// ===========================================================================
__device__ __forceinline__ void layer1_tile_g(
    int b, int ow, int tid,
    const float* __restrict__ data, const float* __restrict__ W1,
    const float* __restrict__ P1, const float* __restrict__ b1v,
    double* __restrict__ dsm, u32* __restrict__ bits)
{
  float* Bsf = (float*)dsm;
  float* As  = (float*)dsm + 2880;

  const int ty = tid >> 5;
  const int tx = tid & 31;
  const int r0 = ty << 3;
  const int c0 = tx << 1;

  const float* abase = data + (size_t)b * (TT * CIN);

  const int slot = tid >> 2;
  const int pair = tid & 3;
  const int tp   = slot - 5;

  const int isub = tid & 7;
  const int oA = tid >> 3;
  const int oB = oA + 32;
  const int boA = ow * 64 + oA;
  const int boB = ow * 64 + oB;
  const bool vB = boB < HID;

  double acc[8][2];
#pragma unroll
  for (int r = 0; r < 8; ++r) { acc[r][0] = 0.0; acc[r][1] = 0.0; }

  float2 aA = make_float2(0.f, 0.f);
  float wA = 0.f, pA = 0.f, wB = 0.f, pB = 0.f;
  if (tid < 220 && tp >= 0)
    aA = *(const float2*)(abase + (size_t)tp * CIN + 2 * pair);
  wA = W1[(size_t)boA * CIN + isub];
  pA = P1[(size_t)boA * CIN + isub];
  if (vB) {
    wB = W1[(size_t)boB * CIN + isub];
    pB = P1[(size_t)boB * CIN + isub];
  }

  for (int i0 = 0; i0 < CIN; i0 += 8) {
    if (tid < 220) {
      As[(2 * pair) * 80 + slot]     = aA.x;
      As[(2 * pair + 1) * 80 + slot] = aA.y;
    }
    {
      const float c  = pA + 2.0f;
      const float E0 = __expf(-0.125f * c * c);
      const float U  = __expf(0.25f * c);
      const float u2 = U * U;
      const float e0 = E0;
      const float e1 = E0 * U * EK1f;
      const float e2 = E0 * u2 * EK2f;
      const float e3 = E0 * (u2 * U) * EK3f;
      const float e4 = E0 * (u2 * u2) * EK4f;
      const float inv = 1.0f / (((((e0 + e1) + e2) + e3) + e4) + 1e-7f);
      float* bp = Bsf + isub * 72 + oA;
      bp[0]    = wA * (e0 * inv);
      bp[576]  = wA * (e1 * inv);
      bp[1152] = wA * (e2 * inv);
      bp[1728] = wA * (e3 * inv);
      bp[2304] = wA * (e4 * inv);
    }
    {
      const float c  = pB + 2.0f;
      const float E0 = __expf(-0.125f * c * c);
      const float U  = __expf(0.25f * c);
      const float u2 = U * U;
      const float e0 = E0;
      const float e1 = E0 * U * EK1f;
      const float e2 = E0 * u2 * EK2f;
      const float e3 = E0 * (u2 * U) * EK3f;
      const float e4 = E0 * (u2 * u2) * EK4f;
      const float inv = 1.0f / (((((e0 + e1) + e2) + e3) + e4) + 1e-7f);
      float* bp = Bsf + isub * 72 + oB;
      bp[0]    = wB * (e0 * inv);
      bp[576]  = wB * (e1 * inv);
      bp[1152] = wB * (e2 * inv);
      bp[1728] = wB * (e3 * inv);
      bp[2304] = wB * (e4 * inv);
    }
    __syncthreads();

    const int i0n = i0 + 8;
    if (i0n < CIN) {
      if (tid < 220 && tp >= 0)
        aA = *(const float2*)(abase + (size_t)tp * CIN + i0n + 2 * pair);
      wA = W1[(size_t)boA * CIN + i0n + isub];
      pA = P1[(size_t)boA * CIN + i0n + isub];
      if (vB) {
        wB = W1[(size_t)boB * CIN + i0n + isub];
        pB = P1[(size_t)boB * CIN + i0n + isub];
      }
    }

    float accf[8][2];
#pragma unroll
    for (int r = 0; r < 8; ++r) { accf[r][0] = 0.f; accf[r][1] = 0.f; }
#pragma unroll
    for (int kk = 0; kk < 8; ++kk) {
      const float* ap = &As[kk * 80 + r0];
      const float4 a0 = *(const float4*)(ap);
      const float4 a1 = *(const float4*)(ap + 4);
      const float4 a2 = *(const float4*)(ap + 8);
      float av[12];
      av[0] = a0.x; av[1] = a0.y; av[2]  = a0.z; av[3]  = a0.w;
      av[4] = a1.x; av[5] = a1.y; av[6]  = a1.z; av[7]  = a1.w;
      av[8] = a2.x; av[9] = a2.y; av[10] = a2.z; av[11] = a2.w;
      float bv[KS][2];
#pragma unroll
      for (int k = 0; k < KS; ++k) {
        const float2 bb = *(const float2*)&Bsf[(k * 8 + kk) * 72 + c0];
        bv[k][0] = bb.x; bv[k][1] = bb.y;
      }
#pragma unroll
      for (int k = 0; k < KS; ++k)
#pragma unroll
        for (int r = 0; r < 8; ++r) {
          accf[r][0] = fmaf(av[r + k], bv[k][0], accf[r][0]);
          accf[r][1] = fmaf(av[r + k], bv[k][1], accf[r][1]);
        }
    }
#pragma unroll
    for (int r = 0; r < 8; ++r) {
      acc[r][0] += (double)accf[r][0];
      acc[r][1] += (double)accf[r][1];
    }
    __syncthreads();
  }

  double* y1s = dsm;
#pragma unroll
  for (int r = 0; r < 8; ++r) {
    const int t = r0 + r;
    if (t < T1) {
      y1s[t * 64 + c0]     = acc[r][0];
      y1s[t * 64 + c0 + 1] = acc[r][1];
    }
  }
  __syncthreads();

  if (tid < 64) {
    const int o = ow * 64 + tid;
    const bool valid = o < HID;
    const double bias = valid ? (double)b1v[o] : 0.0;
    double mem = 0.0;
    for (int t = 0; t < T1; ++t) {
      const double x = y1s[t * 64 + tid] + bias;
      const double reset = (mem > 1.0) ? 1.0 : 0.0;
      mem = __dsub_rn(__dadd_rn(__dmul_rn(0.9, mem), x), reset);
      const unsigned long long mk = __ballot(valid && (mem > 1.0));
      if (tid == 0)  bits[t * 10 + 2 * ow]     = (u32)mk;
      if (tid == 32) bits[t * 10 + 2 * ow + 1] = (u32)(mk >> 32);
    }
  }
  __syncthreads();
}

// ---------------------------------------------------------------------------
// Layer-2 conv + LIF2 (fp32), gbits variant (fallback paths).
// ---------------------------------------------------------------------------
__device__ __forceinline__ void layer2_lif2(
    int b, int tid, float* smem,
    const float* __restrict__ W2, const float* __restrict__ P2,
    const float* __restrict__ b2, float* __restrict__ out)
{
  float* K2s = smem;
  const u32* lbits = (const u32*)(smem + 15000);
  float* y2s = smem + 15510;

  for (int idx = tid; idx < NOUT * HID; idx += 256) {
    const int o = idx / HID, i = idx % HID;
    const float w = W2[idx], p = P2[idx];
    const float c = p + 2.0f;
    float e[KS], s = 0.f;
#pragma unroll
    for (int k = 0; k < KS; ++k) {
      const float d = ((float)k - c) * 0.5f;
      e[k] = __expf(-0.5f * d * d);
      s += e[k];
    }
    const float denom = s + 1e-7f;
#pragma unroll
    for (int k = 0; k < KS; ++k)
      K2s[(o * KS + k) * HID + i] = w * (e[k] / denom);
  }
  __syncthreads();

  for (int task = tid; task < T2 * NOUT; task += 256) {
    const int t2 = task / NOUT, o = task % NOUT;
    float acc = b2[o];
#pragma unroll
    for (int k = 0; k < KS; ++k) {
      const int tp = t2 + k - KS;
      if (tp < 0 || tp >= T1) continue;
      const float* kr = K2s + (o * KS + k) * HID;
      const u32* br = lbits + tp * 10;
      for (int i = 0; i < HID; ++i)
        acc = fmaf((float)((br[i >> 5] >> (i & 31)) & 1u), kr[i], acc);
    }
    y2s[task] = acc;
  }
  __syncthreads();

  if (tid < NOUT) {
    float mem = 0.f;
    for (int t = 0; t < T2; ++t) {
      const float x = y2s[t * NOUT + tid];
      const float reset = (mem > 1.0f) ? 1.0f : 0.0f;
      mem = __fsub_rn(__fadd_rn(__fmul_rn(0.9f, mem), x), reset);
      out[(size_t)t * (BSZ * NOUT) + b * NOUT + tid] = (mem > 1.0f) ? 1.0f : 0.0f;
      out[(size_t)T2 * BSZ * NOUT + (size_t)t * (BSZ * NOUT) + b * NOUT + tid] = mem;
    }
  }
}

// ---------------- fallback kernels ------------------------------------------
__global__ __launch_bounds__(256) void snn_l1(
    const float* __restrict__ data, const float* __restrict__ W1,
    const float* __restrict__ P1, const float* __restrict__ b1v,
    u32* __restrict__ gbits)
{
  __shared__ double dsm[3264];
  const int ow = blockIdx.x, b = blockIdx.y;
  layer1_tile_g(b, ow, threadIdx.x, data, W1, P1, b1v, dsm,
                gbits + (size_t)b * 510);
}

__global__ __launch_bounds__(256) void snn_l2k(
    const u32* __restrict__ gbits,
    const float* __restrict__ W2, const float* __restrict__ P2,
    const float* __restrict__ b2, float* __restrict__ out)
{
  __shared__ float smem[16030];
  const int b = blockIdx.x, tid = threadIdx.x;
  u32* lbits = (u32*)(smem + 15000);
  for (int i = tid; i < 510; i += 256) lbits[i] = gbits[(size_t)b * 510 + i];
  layer2_lif2(b, tid, smem, W2, P2, b2, out);
}

__global__ __launch_bounds__(256) void snn_mono(
    const float* __restrict__ data, const float* __restrict__ W1,
    const float* __restrict__ P1, const float* __restrict__ b1v,
    const float* __restrict__ W2, const float* __restrict__ P2,
    const float* __restrict__ b2, float* __restrict__ out)
{
  __shared__ double dsm[8015];
  const int b = blockIdx.x, tid = threadIdx.x;
  u32* lbits = (u32*)((float*)dsm + 15000);
  for (int ow = 0; ow < 5; ++ow)
    layer1_tile_g(b, ow, tid, data, W1, P1, b1v, dsm, lbits);
  layer2_lif2(b, tid, (float*)dsm, W2, P2, b2, out);
}

// ---------------- launcher --------------------------------------------------
extern "C" void kernel_launch(void* const* d_in, const int* in_sizes, int n_in,
                              void* d_out, int out_size, void* d_ws, size_t ws_size,
                              hipStream_t stream) {
  const float* data = (const float*)d_in[0];
  const float* W1   = (const float*)d_in[1];
  const float* P1   = (const float*)d_in[2];
  const float* b1v  = (const float*)d_in[3];
  const float* W2   = (const float*)d_in[4];
  const float* P2   = (const float*)d_in[5];
  const float* b2   = (const float*)d_in[6];
  float* out = (float*)d_out;

  const size_t BITS_BYTES  = (size_t)BSZ * T1 * 10 * sizeof(u32);   // 261,120
  const size_t K1BF_BYTES  = (size_t)5 * NC32 * KFRAG_U * 2;        // 14,950,400
  const size_t PBUF_BYTES  = (size_t)2 * 5 * 128 * 3264 * 4;        // 16,711,680
  const size_t NEED_S = PBUF_BYTES + K1BF_BYTES;                    // ~31.7 MB
  const size_t K1_OFF_M = 262144;
  const size_t NEED_M = K1_OFF_M + K1BF_BYTES;                      // ~15.2 MB

  if (ws_size >= NEED_S) {
    float* pbuf = (float*)d_ws;
    u16* K1bf   = (u16*)((char*)d_ws + PBUF_BYTES);
    snn_prepm<<<dim3(NC32, 5), 256, 0, stream>>>(W1, P1, K1bf);
    snn_l1s<<<1280, 256, 0, stream>>>(data, K1bf, pbuf);
    snn_l2m<<<BSZ, 256, 0, stream>>>(pbuf, b1v, W2, P2, b2, out);
  } else if (ws_size >= NEED_M) {
    u32* gbits = (u32*)d_ws;
    u16* K1bf  = (u16*)((char*)d_ws + K1_OFF_M);
    snn_prepm<<<dim3(NC32, 5), 256, 0, stream>>>(W1, P1, K1bf);
    snn_l1m<<<640, 256, 0, stream>>>(data, K1bf, b1v, gbits);
    snn_l2k<<<BSZ, 256, 0, stream>>>(gbits, W2, P2, b2, out);
  } else if (ws_size >= BITS_BYTES) {
    u32* gbits = (u32*)d_ws;
    snn_l1<<<dim3(5, BSZ), 256, 0, stream>>>(data, W1, P1, b1v, gbits);
    snn_l2k<<<BSZ, 256, 0, stream>>>(gbits, W2, P2, b2, out);
  } else {
    snn_mono<<<BSZ, 256, 0, stream>>>(data, W1, P1, b1v, W2, P2, b2, out);
  }
}

// Round 9
// 410.831 us; speedup vs baseline: 2.3968x; 2.3968x over previous
//
#include <hip/hip_runtime.h>

// Problem constants
#define BSZ  128
#define TT   50
#define CIN  2312
#define HID  300
#define NOUT 10
#define KS   5
#define T1   51          // (TT+5) - KS + 1
#define T2   52          // (T1+5) - KS + 1

#define NC32 73          // ceil(CIN/32) K-chunks of 32
#define KFRAG_U 20480    // u16 units per (ow,chunk): 5k * 4nt * 2h * 512

typedef unsigned int u32;
typedef unsigned short u16;
typedef __attribute__((ext_vector_type(8))) short s16x8;   // 8 bf16 (4 VGPRs)
typedef __attribute__((ext_vector_type(4))) float f32x4;   // MFMA C/D

// exp(-k^2/8) constants, k=1..4 (fp32)
#define EK1f 0.88249690258459546f
#define EK2f 0.60653065971263342f
#define EK3f 0.32465246735834974f
#define EK4f 0.13533528323661270f

static __device__ __forceinline__ u16 bfhi(float x) {
  u32 u = __float_as_uint(x);
  return (u16)((u + 0x7fffu + ((u >> 16) & 1u)) >> 16);   // RNE bf16
}
static __device__ __forceinline__ float bf2f(u16 h) {
  return __uint_as_float(((u32)h) << 16);
}

// ===========================================================================
// prep: synthesize gauss kernel once, split into bf16 hi/lo, in exact MFMA
// B-fragment order: [ow][chunk][k][nt][h][lane][8] (frag = 64 lanes x 16 B).
// ===========================================================================
__global__ __launch_bounds__(256) void snn_prepm(
    const float* __restrict__ W1, const float* __restrict__ P1,
    u16* __restrict__ K1bf)
{
  const int c  = blockIdx.x;          // 0..72
  const int ow = blockIdx.y;          // 0..4
  const int tid = threadIdx.x;
  const int nt = tid >> 6, ll = tid & 63;
  const int g = ll >> 4, lr = ll & 15;
  const int o  = ow * 64 + nt * 16 + lr;
  const int ib = c * 32 + g * 8;

  s16x8 hv[5], lv[5];
#pragma unroll
  for (int k = 0; k < 5; ++k)
#pragma unroll
    for (int j = 0; j < 8; ++j) { hv[k][j] = 0; lv[k][j] = 0; }

  if (o < HID) {
    const float* wrow = W1 + (size_t)o * CIN;
    const float* prow = P1 + (size_t)o * CIN;
#pragma unroll
    for (int j = 0; j < 8; ++j) {
      const int i = ib + j;
      if (i < CIN) {
        const float w1 = wrow[i], p1 = prow[i];
        const float cc = p1 + 2.0f;
        const float E0 = __expf(-0.125f * cc * cc);
        const float U  = __expf(0.25f * cc);
        const float u2 = U * U;
        const float e0 = E0;
        const float e1 = E0 * U * EK1f;
        const float e2 = E0 * u2 * EK2f;
        const float e3 = E0 * (u2 * U) * EK3f;
        const float e4 = E0 * (u2 * u2) * EK4f;
        const float inv = 1.0f / (((((e0 + e1) + e2) + e3) + e4) + 1e-7f);
        const float vk[5] = { w1 * (e0 * inv), w1 * (e1 * inv),
                              w1 * (e2 * inv), w1 * (e3 * inv),
                              w1 * (e4 * inv) };
#pragma unroll
        for (int k = 0; k < 5; ++k) {
          const u16 h = bfhi(vk[k]);
          const u16 lo = bfhi(vk[k] - bf2f(h));
          hv[k][j] = (short)h; lv[k][j] = (short)lo;
        }
      }
    }
  }
  u16* base = K1bf + ((size_t)ow * NC32 + c) * KFRAG_U + nt * 1024 + ll * 8;
#pragma unroll
  for (int k = 0; k < 5; ++k) {
    *(s16x8*)(base + k * 4096)       = hv[k];
    *(s16x8*)(base + k * 4096 + 512) = lv[k];
  }
}

// ===========================================================================
// Layer-1 split-K MFMA kernel (round-5 proven structure, K halved per block).
// 1280 blocks: (s, ow, b) with s = K-half. Each block: C[64t][64o] partial
// over chunks [c_lo, c_hi), mfma_f32_16x16x32_bf16, 3-term bf16 split,
// per-chunk fp64 promotion, result stored as fp32 partial to pbuf.
// Waves 2x2; A double-buffered LDS, natural stride-80B banking; B rolling
// per-tap register reload.
// ROUND-9 FIX: __launch_bounds__(256, 2) — round 8's (256,4) capped the
// allocator at 64 VGPR -> massive scratch spills (WRITE_SIZE 1.6 GB,
// MfmaUtil 8.8%). At the natural ~84-100 VGPR (r5/r7 measured), occupancy
// steps (m69) still give 4 waves/SIMD = 4 blocks/CU resident, which the
// 1280-block grid (5/CU supplied) can now actually fill.
// LDS: 2 x (hi 2720 + lo 2720) u16 = 21760 B.
// ===========================================================================
__global__ __launch_bounds__(256, 2) void snn_l1s(
    const float* __restrict__ data, const u16* __restrict__ K1bf,
    float* __restrict__ pbuf)
{
  __shared__ __align__(16) double dsm[2720];   // 21760 B
  u16* A16 = (u16*)dsm;

  const int tid = threadIdx.x;
  const int bid = blockIdx.x;
  const int g  = bid & 7;            // XCD
  const int r  = bid >> 3;           // 0..159
  const int s  = r & 1;              // K-half
  const int u  = r >> 1;             // 0..79
  const int x  = g * 80 + u;         // pair rank 0..639 (ow-major per XCD)
  const int ow = x >> 7;             // 0..4
  const int b  = x & 127;

  const int c_lo = s ? 37 : 0;
  const int c_hi = s ? 73 : 37;

  const int w  = tid >> 6, l = tid & 63;
  const int lr = l & 15, lg = l >> 4;
  const int wr = w >> 1, wc = w & 1;
  const int abase_u = (32 * wr + lr) * 40 + lg * 8;   // A-frag base (u16)

  const float* dbase = data + (size_t)b * (TT * CIN);
  const u16* kbn = K1bf + (size_t)ow * NC32 * KFRAG_U + l * 8;
  const int ntg0 = wc * 2, ntg1 = wc * 2 + 1;

  // A staging thread mapping: slot s1 (0..63), i-group j4 (0..3)
  const int s1 = tid >> 2;
  const int j4 = tid & 3;
  const int tp = s1 - 5;
  const bool avld = (tp >= 0) && (tp < TT);
  const float* aptr = dbase + (size_t)(avld ? tp : 0) * CIN + j4 * 8;

  // zero pad rows 64..67 (tap overhang) in both buffers, hi+lo
  if (tid < 80) {
    s16x8 z;
#pragma unroll
    for (int j = 0; j < 8; ++j) z[j] = 0;
    const int rr = tid / 20, off = (tid % 20) * 8;
    *(s16x8*)(A16 + rr * 2720 + 2560 + off) = z;
  }

#define LOADA(CC)                                                             \
  {                                                                           \
    const bool iv_ = avld && (((CC) < 72) || (j4 == 0));                      \
    const float* pp_ = aptr + (size_t)(CC) * 32;                              \
    ra0 = iv_ ? *(const float4*)(pp_)     : make_float4(0.f, 0.f, 0.f, 0.f);  \
    ra1 = iv_ ? *(const float4*)(pp_ + 4) : make_float4(0.f, 0.f, 0.f, 0.f);  \
  }

#define STAGE_A(CC)                                                           \
  {                                                                           \
    const float f_[8] = { ra0.x, ra0.y, ra0.z, ra0.w,                         \
                          ra1.x, ra1.y, ra1.z, ra1.w };                       \
    s16x8 hv_, lv_;                                                           \
    _Pragma("unroll")                                                         \
    for (int j = 0; j < 8; ++j) {                                             \
      const u16 h_ = bfhi(f_[j]);                                             \
      hv_[j] = (short)h_;                                                     \
      lv_[j] = (short)bfhi(f_[j] - bf2f(h_));                                 \
    }                                                                         \
    u16* bn_ = A16 + ((CC) & 1) * 5440;                                       \
    const int woff_ = s1 * 40 + j4 * 8;                                       \
    *(s16x8*)(bn_ + woff_) = hv_;                                             \
    *(s16x8*)(bn_ + 2720 + woff_) = lv_;                                      \
  }

  // ---- B frag registers: 20 per wave, rolling per-tap reload ----
  s16x8 bh[5][2], bl[5][2];
#pragma unroll
  for (int k = 0; k < 5; ++k) {
    const u16* cb_ = kbn + (size_t)c_lo * KFRAG_U + k * 4096;
    bh[k][0] = *(const s16x8*)(cb_ + ntg0 * 1024);
    bh[k][1] = *(const s16x8*)(cb_ + ntg1 * 1024);
    bl[k][0] = *(const s16x8*)(cb_ + ntg0 * 1024 + 512);
    bl[k][1] = *(const s16x8*)(cb_ + ntg1 * 1024 + 512);
  }

  f32x4 accf[2][2];
  double accd[2][2][4];
#pragma unroll
  for (int m = 0; m < 2; ++m)
#pragma unroll
    for (int n = 0; n < 2; ++n)
#pragma unroll
      for (int q = 0; q < 4; ++q) { accf[m][n][q] = 0.f; accd[m][n][q] = 0.0; }

  // ---- prologue: stage chunk c_lo; prefetch A regs <- c_lo+1 ----
  float4 ra0, ra1;
  LOADA(c_lo);
  STAGE_A(c_lo);
  LOADA(c_lo + 1);
  __syncthreads();

  // ---- main loop: per-chunk barrier (round-5 proven schedule) ----
  for (int c = c_lo; c < c_hi; ++c) {
    // stage next chunk into the other buffer; prefetch A regs <- c+2
    if (c + 1 < c_hi) {
      STAGE_A(c + 1);
      if (c + 2 < c_hi) LOADA(c + 2);
    }

    // compute chunk c: 5 taps x (2m x 2n) x 3 terms; rolling B reload <- c+1
    {
      const u16* bc_ = A16 + (c & 1) * 5440;
      const int rc = c + 1;
#pragma unroll
      for (int k = 0; k < 5; ++k) {
        const s16x8 ah0 = *(const s16x8*)(bc_ + abase_u + k * 40);
        const s16x8 al0 = *(const s16x8*)(bc_ + 2720 + abase_u + k * 40);
        const s16x8 ah1 = *(const s16x8*)(bc_ + abase_u + (16 + k) * 40);
        const s16x8 al1 = *(const s16x8*)(bc_ + 2720 + abase_u + (16 + k) * 40);

        accf[0][0] = __builtin_amdgcn_mfma_f32_16x16x32_bf16(ah0, bh[k][0], accf[0][0], 0, 0, 0);
        accf[0][0] = __builtin_amdgcn_mfma_f32_16x16x32_bf16(al0, bh[k][0], accf[0][0], 0, 0, 0);
        accf[0][0] = __builtin_amdgcn_mfma_f32_16x16x32_bf16(ah0, bl[k][0], accf[0][0], 0, 0, 0);

        accf[0][1] = __builtin_amdgcn_mfma_f32_16x16x32_bf16(ah0, bh[k][1], accf[0][1], 0, 0, 0);
        accf[0][1] = __builtin_amdgcn_mfma_f32_16x16x32_bf16(al0, bh[k][1], accf[0][1], 0, 0, 0);
        accf[0][1] = __builtin_amdgcn_mfma_f32_16x16x32_bf16(ah0, bl[k][1], accf[0][1], 0, 0, 0);

        accf[1][0] = __builtin_amdgcn_mfma_f32_16x16x32_bf16(ah1, bh[k][0], accf[1][0], 0, 0, 0);
        accf[1][0] = __builtin_amdgcn_mfma_f32_16x16x32_bf16(al1, bh[k][0], accf[1][0], 0, 0, 0);
        accf[1][0] = __builtin_amdgcn_mfma_f32_16x16x32_bf16(ah1, bl[k][0], accf[1][0], 0, 0, 0);

        accf[1][1] = __builtin_amdgcn_mfma_f32_16x16x32_bf16(ah1, bh[k][1], accf[1][1], 0, 0, 0);
        accf[1][1] = __builtin_amdgcn_mfma_f32_16x16x32_bf16(al1, bh[k][1], accf[1][1], 0, 0, 0);
        accf[1][1] = __builtin_amdgcn_mfma_f32_16x16x32_bf16(ah1, bl[k][1], accf[1][1], 0, 0, 0);

        if (rc < c_hi) {
          const u16* cb_ = kbn + (size_t)rc * KFRAG_U + k * 4096;
          bh[k][0] = *(const s16x8*)(cb_ + ntg0 * 1024);
          bh[k][1] = *(const s16x8*)(cb_ + ntg1 * 1024);
          bl[k][0] = *(const s16x8*)(cb_ + ntg0 * 1024 + 512);
          bl[k][1] = *(const s16x8*)(cb_ + ntg1 * 1024 + 512);
        }
      }
    }

    // promote chunk partial into fp64
#pragma unroll
    for (int m = 0; m < 2; ++m)
#pragma unroll
      for (int n = 0; n < 2; ++n)
#pragma unroll
        for (int q = 0; q < 4; ++q) {
          accd[m][n][q] += (double)accf[m][n][q];
          accf[m][n][q] = 0.f;
        }
    __syncthreads();
  }
#undef LOADA
#undef STAGE_A

  // ---- store fp32 partial tile [51][64] ----
  // C/D layout: col = lane&15, row = (lane>>4)*4 + reg
  float* pb = pbuf + (((size_t)s * 5 + ow) * 128 + b) * 3264;
#pragma unroll
  for (int m = 0; m < 2; ++m)
#pragma unroll
    for (int n = 0; n < 2; ++n)
#pragma unroll
      for (int q = 0; q < 4; ++q) {
        const int t = 32 * wr + 16 * m + lg * 4 + q;
        if (t < T1) pb[t * 64 + 32 * wc + 16 * n + lr] = (float)accd[m][n][q];
      }
}

// ===========================================================================
// Fused layer-2: reduce split-K partials + LIF1 + ballot + conv2 + LIF2.
// 128 blocks (one per batch). smem floats: [0,15000) K2s [o][k][i],
// [15000,15510) lbits u32, [15510,16030) y2s [t2][o].
// ===========================================================================
__global__ __launch_bounds__(256) void snn_l2m(
    const float* __restrict__ pbuf, const float* __restrict__ b1v,
    const float* __restrict__ W2, const float* __restrict__ P2,
    const float* __restrict__ b2, float* __restrict__ out)
{
  __shared__ float smem[16030];
  const int b = blockIdx.x, tid = threadIdx.x;
  float* K2s = smem;
  u32* lbits = (u32*)(smem + 15000);
  float* y2s = smem + 15510;

  // ---- K2 synthesis (all 256 threads) ----
  for (int idx = tid; idx < NOUT * HID; idx += 256) {
    const int o = idx / HID, i = idx % HID;
    const float w = W2[idx], p = P2[idx];
    const float c = p + 2.0f;
    float e[KS], ssum = 0.f;
#pragma unroll
    for (int k = 0; k < KS; ++k) {
      const float d = ((float)k - c) * 0.5f;
      e[k] = __expf(-0.5f * d * d);
      ssum += e[k];
    }
    const float denom = ssum + 1e-7f;
#pragma unroll
    for (int k = 0; k < KS; ++k)
      K2s[(o * KS + k) * HID + i] = w * (e[k] / denom);
  }

  // ---- fused reduce + LIF1 + ballot: wave w handles ow = w (+4) ----
  {
    const int w = tid >> 6, l = tid & 63;
    for (int ow = w; ow < 5; ow += 4) {
      const int o = ow * 64 + l;
      const bool valid = o < HID;
      const double bias = valid ? (double)b1v[o] : 0.0;
      const float* p0 = pbuf + (((size_t)0 * 5 + ow) * 128 + b) * 3264 + l;
      const float* p1 = pbuf + (((size_t)1 * 5 + ow) * 128 + b) * 3264 + l;
      double mem = 0.0;
      for (int t = 0; t < T1; ++t) {
        const double x = (double)p0[t * 64] + (double)p1[t * 64] + bias;
        const double reset = (mem > 1.0) ? 1.0 : 0.0;
        mem = __dsub_rn(__dadd_rn(__dmul_rn(0.9, mem), x), reset);
        const unsigned long long mk = __ballot(valid && (mem > 1.0));
        if (l == 0)  lbits[t * 10 + 2 * ow]     = (u32)mk;
        if (l == 32) lbits[t * 10 + 2 * ow + 1] = (u32)(mk >> 32);
      }
    }
  }
  __syncthreads();                    // fences K2s + lbits

  // ---- conv2 ----
  for (int task = tid; task < T2 * NOUT; task += 256) {
    const int t2 = task / NOUT, o = task % NOUT;
    float acc = b2[o];
#pragma unroll
    for (int k = 0; k < KS; ++k) {
      const int tp = t2 + k - KS;
      if (tp < 0 || tp >= T1) continue;
      const float* kr = K2s + (o * KS + k) * HID;
      const u32* br = lbits + tp * 10;
      for (int i = 0; i < HID; ++i)
        acc = fmaf((float)((br[i >> 5] >> (i & 31)) & 1u), kr[i], acc);
    }
    y2s[task] = acc;
  }
  __syncthreads();

  // ---- LIF2 + output ----
  if (tid < NOUT) {
    float mem = 0.f;
    for (int t = 0; t < T2; ++t) {
      const float x = y2s[t * NOUT + tid];
      const float reset = (mem > 1.0f) ? 1.0f : 0.0f;
      mem = __fsub_rn(__fadd_rn(__fmul_rn(0.9f, mem), x), reset);
      out[(size_t)t * (BSZ * NOUT) + b * NOUT + tid] = (mem > 1.0f) ? 1.0f : 0.0f;
      out[(size_t)T2 * BSZ * NOUT + (size_t)t * (BSZ * NOUT) + b * NOUT + tid] = mem;
    }
  }
}

// ===========================================================================
// Fallback 1: round-5 proven l1m (full-K per block, gbits output) — used
// when workspace fits K1bf but not the split-K partial buffer.
// ===========================================================================
__global__ __launch_bounds__(256, 2) void snn_l1m(
    const float* __restrict__ data, const u16* __restrict__ K1bf,
    const float* __restrict__ b1v, u32* __restrict__ gbits)
{
  __shared__ double dsm[3264];         // 26112 B
  u16* A16 = (u16*)dsm;

  const int tid = threadIdx.x;
  const int bid = blockIdx.x;
  const int rnk = (bid & 7) * 80 + (bid >> 3);
  const int ow = rnk >> 7;
  const int b  = rnk & 127;

  const int w  = tid >> 6, l = tid & 63;
  const int lr = l & 15, lg = l >> 4;
  const int wr = w >> 1, wc = w & 1;
  const int abase_u = (32 * wr + lr) * 40 + lg * 8;

  const float* dbase = data + (size_t)b * (TT * CIN);
  const u16* kbn = K1bf + (size_t)ow * NC32 * KFRAG_U + l * 8;
  const int ntg0 = wc * 2, ntg1 = wc * 2 + 1;

  const int s1 = tid >> 2;
  const int j4 = tid & 3;
  const int tp = s1 - 5;
  const bool avld = (tp >= 0) && (tp < TT);
  const float* aptr = dbase + (size_t)(avld ? tp : 0) * CIN + j4 * 8;

  if (tid < 80) {
    s16x8 z;
#pragma unroll
    for (int j = 0; j < 8; ++j) z[j] = 0;
    const int rr = tid / 20, off = (tid % 20) * 8;
    *(s16x8*)(A16 + rr * 2720 + 2560 + off) = z;
  }

#define LOADA(CC)                                                             \
  {                                                                           \
    const bool iv_ = avld && (((CC) < 72) || (j4 == 0));                      \
    const float* pp_ = aptr + (size_t)(CC) * 32;                              \
    ra0 = iv_ ? *(const float4*)(pp_)     : make_float4(0.f, 0.f, 0.f, 0.f);  \
    ra1 = iv_ ? *(const float4*)(pp_ + 4) : make_float4(0.f, 0.f, 0.f, 0.f);  \
  }

#define STAGE_A(CC)                                                           \
  {                                                                           \
    const float f_[8] = { ra0.x, ra0.y, ra0.z, ra0.w,                         \
                          ra1.x, ra1.y, ra1.z, ra1.w };                       \
    s16x8 hv_, lv_;                                                           \
    _Pragma("unroll")                                                         \
    for (int j = 0; j < 8; ++j) {                                             \
      const u16 h_ = bfhi(f_[j]);                                             \
      hv_[j] = (short)h_;                                                     \
      lv_[j] = (short)bfhi(f_[j] - bf2f(h_));                                 \
    }                                                                         \
    u16* bn_ = A16 + ((CC) & 1) * 5440;                                       \
    const int woff_ = s1 * 40 + j4 * 8;                                       \
    *(s16x8*)(bn_ + woff_) = hv_;                                             \
    *(s16x8*)(bn_ + 2720 + woff_) = lv_;                                      \
  }

  s16x8 bh[5][2], bl[5][2];
#pragma unroll
  for (int k = 0; k < 5; ++k) {
    const u16* cb_ = kbn + k * 4096;
    bh[k][0] = *(const s16x8*)(cb_ + ntg0 * 1024);
    bh[k][1] = *(const s16x8*)(cb_ + ntg1 * 1024);
    bl[k][0] = *(const s16x8*)(cb_ + ntg0 * 1024 + 512);
    bl[k][1] = *(const s16x8*)(cb_ + ntg1 * 1024 + 512);
  }

  f32x4 accf[2][2];
  double accd[2][2][4];
#pragma unroll
  for (int m = 0; m < 2; ++m)
#pragma unroll
    for (int n = 0; n < 2; ++n)
#pragma unroll
      for (int q = 0; q < 4; ++q) { accf[m][n][q] = 0.f; accd[m][n][q] = 0.0; }

  float4 ra0, ra1;
  LOADA(0);
  STAGE_A(0);
  LOADA(1);
  __syncthreads();

  for (int c = 0; c < NC32; ++c) {
    if (c + 1 < NC32) {
      STAGE_A(c + 1);
      if (c + 2 < NC32) LOADA(c + 2);
    }
    {
      const u16* bc_ = A16 + (c & 1) * 5440;
      const int rc = c + 1;
#pragma unroll
      for (int k = 0; k < 5; ++k) {
        const s16x8 ah0 = *(const s16x8*)(bc_ + abase_u + k * 40);
        const s16x8 al0 = *(const s16x8*)(bc_ + 2720 + abase_u + k * 40);
        const s16x8 ah1 = *(const s16x8*)(bc_ + abase_u + (16 + k) * 40);
        const s16x8 al1 = *(const s16x8*)(bc_ + 2720 + abase_u + (16 + k) * 40);

        accf[0][0] = __builtin_amdgcn_mfma_f32_16x16x32_bf16(ah0, bh[k][0], accf[0][0], 0, 0, 0);
        accf[0][0] = __builtin_amdgcn_mfma_f32_16x16x32_bf16(al0, bh[k][0], accf[0][0], 0, 0, 0);
        accf[0][0] = __builtin_amdgcn_mfma_f32_16x16x32_bf16(ah0, bl[k][0], accf[0][0], 0, 0, 0);
        accf[0][1] = __builtin_amdgcn_mfma_f32_16x16x32_bf16(ah0, bh[k][1], accf[0][1], 0, 0, 0);
        accf[0][1] = __builtin_amdgcn_mfma_f32_16x16x32_bf16(al0, bh[k][1], accf[0][1], 0, 0, 0);
        accf[0][1] = __builtin_amdgcn_mfma_f32_16x16x32_bf16(ah0, bl[k][1], accf[0][1], 0, 0, 0);
        accf[1][0] = __builtin_amdgcn_mfma_f32_16x16x32_bf16(ah1, bh[k][0], accf[1][0], 0, 0, 0);
        accf[1][0] = __builtin_amdgcn_mfma_f32_16x16x32_bf16(al1, bh[k][0], accf[1][0], 0, 0, 0);
        accf[1][0] = __builtin_amdgcn_mfma_f32_16x16x32_bf16(ah1, bl[k][0], accf[1][0], 0, 0, 0);
        accf[1][1] = __builtin_amdgcn_mfma_f32_16x16x32_bf16(ah1, bh[k][1], accf[1][1], 0, 0, 0);
        accf[1][1] = __builtin_amdgcn_mfma_f32_16x16x32_bf16(al1, bh[k][1], accf[1][1], 0, 0, 0);
        accf[1][1] = __builtin_amdgcn_mfma_f32_16x16x32_bf16(ah1, bl[k][1], accf[1][1], 0, 0, 0);

        if (rc < NC32) {
          const u16* cb_ = kbn + (size_t)rc * KFRAG_U + k * 4096;
          bh[k][0] = *(const s16x8*)(cb_ + ntg0 * 1024);
          bh[k][1] = *(const s16x8*)(cb_ + ntg1 * 1024);
          bl[k][0] = *(const s16x8*)(cb_ + ntg0 * 1024 + 512);
          bl[k][1] = *(const s16x8*)(cb_ + ntg1 * 1024 + 512);
        }
      }
    }
#pragma unroll
    for (int m = 0; m < 2; ++m)
#pragma unroll
      for (int n = 0; n < 2; ++n)
#pragma unroll
        for (int q = 0; q < 4; ++q) {
          accd[m][n][q] += (double)accf[m][n][q];
          accf[m][n][q] = 0.f;
        }
    __syncthreads();
  }
#undef LOADA
#undef STAGE_A

  double* y1s = dsm;
#pragma unroll
  for (int m = 0; m < 2; ++m)
#pragma unroll
    for (int n = 0; n < 2; ++n)
#pragma unroll
      for (int q = 0; q < 4; ++q) {
        const int t = 32 * wr + 16 * m + lg * 4 + q;
        if (t < T1) y1s[t * 64 + 32 * wc + 16 * n + lr] = accd[m][n][q];
      }
  __syncthreads();

  if (tid < 64) {
    const int o = ow * 64 + tid;
    const bool valid = o < HID;
    const double bias = valid ? (double)b1v[o] : 0.0;
    u32* bits = gbits + (size_t)b * 510;
    double mem = 0.0;
    for (int t = 0; t < T1; ++t) {
      const double x = y1s[t * 64 + tid] + bias;
      const double reset = (mem > 1.0) ? 1.0 : 0.0;
      mem = __dsub_rn(__dadd_rn(__dmul_rn(0.9, mem), x), reset);
      const unsigned long long mk = __ballot(valid && (mem > 1.0));
      if (tid == 0)  bits[t * 10 + 2 * ow]     = (u32)mk;
      if (tid == 32) bits[t * 10 + 2 * ow + 1] = (u32)(mk >> 32);
    }
  }
}

// ===========================================================================
// Fallback 2: fp32 layer-1 (gauss in-kernel) — round-1/2 proven path.
// ===========================================================================
__device__ __forceinline__ void layer1_tile_g(
    int b, int ow, int tid,
    const float* __restrict__ data, const float* __restrict__ W1,
    const float* __restrict__ P1, const float* __restrict__ b1v,
    double* __restrict__ dsm, u32* __restrict__ bits)
{
  float* Bsf = (float*)dsm;
  float* As  = (float*)dsm + 2880;

  const int ty = tid >> 5;
  const int tx = tid & 31;
  const int r0 = ty << 3;
  const int c0 = tx << 1;

  const float* abase = data + (size_t)b * (TT * CIN);

  const int slot = tid >> 2;
  const int pair = tid & 3;
  const int tp   = slot - 5;

  const int isub = tid & 7;
  const int oA = tid >> 3;
  const int oB = oA + 32;
  const int boA = ow * 64 + oA;
  const int boB = ow * 64 + oB;
  const bool vB = boB < HID;

  double acc[8][2];
#pragma unroll
  for (int r = 0; r < 8; ++r) { acc[r][0] = 0.0; acc[r][1] = 0.0; }

  float2 aA = make_float2(0.f, 0.f);
  float wA = 0.f, pA = 0.f, wB = 0.f, pB = 0.f;
  if (tid < 220 && tp >= 0)
    aA = *(const float2*)(abase + (size_t)tp * CIN + 2 * pair);
  wA = W1[(size_t)boA * CIN + isub];
  pA = P1[(size_t)boA * CIN + isub];
  if (vB) {
    wB = W1[(size_t)boB * CIN + isub];
    pB = P1[(size_t)boB * CIN + isub];
  }

  for (int i0 = 0; i0 < CIN; i0 += 8) {
    if (tid < 220) {
      As[(2 * pair) * 80 + slot]     = aA.x;
      As[(2 * pair + 1) * 80 + slot] = aA.y;
    }
    {
      const float c  = pA + 2.0f;
      const float E0 = __expf(-0.125f * c * c);
      const float U  = __expf(0.25f * c);
      const float u2 = U * U;
      const float e0 = E0;
      const float e1 = E0 * U * EK1f;
      const float e2 = E0 * u2 * EK2f;
      const float e3 = E0 * (u2 * U) * EK3f;
      const float e4 = E0 * (u2 * u2) * EK4f;
      const float inv = 1.0f / (((((e0 + e1) + e2) + e3) + e4) + 1e-7f);
      float* bp = Bsf + isub * 72 + oA;
      bp[0]    = wA * (e0 * inv);
      bp[576]  = wA * (e1 * inv);
      bp[1152] = wA * (e2 * inv);
      bp[1728] = wA * (e3 * inv);
      bp[2304] = wA * (e4 * inv);
    }
    {
      const float c  = pB + 2.0f;
      const float E0 = __expf(-0.125f * c * c);
      const float U  = __expf(0.25f * c);
      const float u2 = U * U;
      const float e0 = E0;
      const float e1 = E0 * U * EK1f;
      const float e2 = E0 * u2 * EK2f;
      const float e3 = E0 * (u2 * U) * EK3f;
      const float e4 = E0 * (u2 * u2) * EK4f;
      const float inv = 1.0f / (((((e0 + e1) + e2) + e3) + e4) + 1e-7f);
      float* bp = Bsf + isub * 72 + oB;
      bp[0]    = wB * (e0 * inv);
      bp[576]  = wB * (e1 * inv);
      bp[1152] = wB * (e2 * inv);
      bp[1728] = wB * (e3 * inv);
      bp[2304] = wB * (e4 * inv);
    }
    __syncthreads();

    const int i0n = i0 + 8;
    if (i0n < CIN) {
      if (tid < 220 && tp >= 0)
        aA = *(const float2*)(abase + (size_t)tp * CIN + i0n + 2 * pair);
      wA = W1[(size_t)boA * CIN + i0n + isub];
      pA = P1[(size_t)boA * CIN + i0n + isub];
      if (vB) {
        wB = W1[(size_t)boB * CIN + i0n + isub];
        pB = P1[(size_t)boB * CIN + i0n + isub];
      }
    }

    float accf[8][2];
#pragma unroll
    for (int r = 0; r < 8; ++r) { accf[r][0] = 0.f; accf[r][1] = 0.f; }
#pragma unroll
    for (int kk = 0; kk < 8; ++kk) {
      const float* ap = &As[kk * 80 + r0];
      const float4 a0 = *(const float4*)(ap);
      const float4 a1 = *(const float4*)(ap + 4);
      const float4 a2 = *(const float4*)(ap + 8);
      float av[12];
      av[0] = a0.x; av[1] = a0.y; av[2]  = a0.z; av[3]  = a0.w;
      av[4] = a1.x; av[5] = a1.y; av[6]  = a1.z; av[7]  = a1.w;
      av[8] = a2.x; av[9] = a2.y; av[10] = a2.z; av[11] = a2.w;
      float bv[KS][2];
#pragma unroll
      for (int k = 0; k < KS; ++k) {
        const float2 bb = *(const float2*)&Bsf[(k * 8 + kk) * 72 + c0];
        bv[k][0] = bb.x; bv[k][1] = bb.y;
      }
#pragma unroll
      for (int k = 0; k < KS; ++k)
#pragma unroll
        for (int r = 0; r < 8; ++r) {
          accf[r][0] = fmaf(av[r + k], bv[k][0], accf[r][0]);
          accf[r][1] = fmaf(av[r + k], bv[k][1], accf[r][1]);
        }
    }
#pragma unroll
    for (int r = 0; r < 8; ++r) {
      acc[r][0] += (double)accf[r][0];
      acc[r][1] += (double)accf[r][1];
    }
    __syncthreads();
  }

  double* y1s = dsm;
#pragma unroll
  for (int r = 0; r < 8; ++r) {
    const int t = r0 + r;
    if (t < T1) {
      y1s[t * 64 + c0]     = acc[r][0];
      y1s[t * 64 + c0 + 1] = acc[r][1];
    }
  }
  __syncthreads();

  if (tid < 64) {
    const int o = ow * 64 + tid;
    const bool valid = o < HID;
    const double bias = valid ? (double)b1v[o] : 0.0;
    double mem = 0.0;
    for (int t = 0; t < T1; ++t) {
      const double x = y1s[t * 64 + tid] + bias;
      const double reset = (mem > 1.0) ? 1.0 : 0.0;
      mem = __dsub_rn(__dadd_rn(__dmul_rn(0.9, mem), x), reset);
      const unsigned long long mk = __ballot(valid && (mem > 1.0));
      if (tid == 0)  bits[t * 10 + 2 * ow]     = (u32)mk;
      if (tid == 32) bits[t * 10 + 2 * ow + 1] = (u32)(mk >> 32);
    }
  }
  __syncthreads();
}

// ---------------------------------------------------------------------------
// Layer-2 conv + LIF2 (fp32), gbits variant (fallback paths).
// ---------------------------------------------------------------------------
__device__ __forceinline__ void layer2_lif2(
    int b, int tid, float* smem,
    const float* __restrict__ W2, const float* __restrict__ P2,
    const float* __restrict__ b2, float* __restrict__ out)
{
  float* K2s = smem;
  const u32* lbits = (const u32*)(smem + 15000);
  float* y2s = smem + 15510;

  for (int idx = tid; idx < NOUT * HID; idx += 256) {
    const int o = idx / HID, i = idx % HID;
    const float w = W2[idx], p = P2[idx];
    const float c = p + 2.0f;
    float e[KS], s = 0.f;
#pragma unroll
    for (int k = 0; k < KS; ++k) {
      const float d = ((float)k - c) * 0.5f;
      e[k] = __expf(-0.5f * d * d);
      s += e[k];
    }
    const float denom = s + 1e-7f;
#pragma unroll
    for (int k = 0; k < KS; ++k)
      K2s[(o * KS + k) * HID + i] = w * (e[k] / denom);
  }
  __syncthreads();

  for (int task = tid; task < T2 * NOUT; task += 256) {
    const int t2 = task / NOUT, o = task % NOUT;
    float acc = b2[o];
#pragma unroll
    for (int k = 0; k < KS; ++k) {
      const int tp = t2 + k - KS;
      if (tp < 0 || tp >= T1) continue;
      const float* kr = K2s + (o * KS + k) * HID;
      const u32* br = lbits + tp * 10;
      for (int i = 0; i < HID; ++i)
        acc = fmaf((float)((br[i >> 5] >> (i & 31)) & 1u), kr[i], acc);
    }
    y2s[task] = acc;
  }
  __syncthreads();

  if (tid < NOUT) {
    float mem = 0.f;
    for (int t = 0; t < T2; ++t) {
      const float x = y2s[t * NOUT + tid];
      const float reset = (mem > 1.0f) ? 1.0f : 0.0f;
      mem = __fsub_rn(__fadd_rn(__fmul_rn(0.9f, mem), x), reset);
      out[(size_t)t * (BSZ * NOUT) + b * NOUT + tid] = (mem > 1.0f) ? 1.0f : 0.0f;
      out[(size_t)T2 * BSZ * NOUT + (size_t)t * (BSZ * NOUT) + b * NOUT + tid] = mem;
    }
  }
}

// ---------------- fallback kernels ------------------------------------------
__global__ __launch_bounds__(256) void snn_l1(
    const float* __restrict__ data, const float* __restrict__ W1,
    const float* __restrict__ P1, const float* __restrict__ b1v,
    u32* __restrict__ gbits)
{
  __shared__ double dsm[3264];
  const int ow = blockIdx.x, b = blockIdx.y;
  layer1_tile_g(b, ow, threadIdx.x, data, W1, P1, b1v, dsm,
                gbits + (size_t)b * 510);
}

__global__ __launch_bounds__(256) void snn_l2k(
    const u32* __restrict__ gbits,
    const float* __restrict__ W2, const float* __restrict__ P2,
    const float* __restrict__ b2, float* __restrict__ out)
{
  __shared__ float smem[16030];
  const int b = blockIdx.x, tid = threadIdx.x;
  u32* lbits = (u32*)(smem + 15000);
  for (int i = tid; i < 510; i += 256) lbits[i] = gbits[(size_t)b * 510 + i];
  layer2_lif2(b, tid, smem, W2, P2, b2, out);
}

__global__ __launch_bounds__(256) void snn_mono(
    const float* __restrict__ data, const float* __restrict__ W1,
    const float* __restrict__ P1, const float* __restrict__ b1v,
    const float* __restrict__ W2, const float* __restrict__ P2,
    const float* __restrict__ b2, float* __restrict__ out)
{
  __shared__ double dsm[8015];
  const int b = blockIdx.x, tid = threadIdx.x;
  u32* lbits = (u32*)((float*)dsm + 15000);
  for (int ow = 0; ow < 5; ++ow)
    layer1_tile_g(b, ow, tid, data, W1, P1, b1v, dsm, lbits);
  layer2_lif2(b, tid, (float*)dsm, W2, P2, b2, out);
}

// ---------------- launcher --------------------------------------------------
extern "C" void kernel_launch(void* const* d_in, const int* in_sizes, int n_in,
                              void* d_out, int out_size, void* d_ws, size_t ws_size,
                              hipStream_t stream) {
  const float* data = (const float*)d_in[0];
  const float* W1   = (const float*)d_in[1];
  const float* P1   = (const float*)d_in[2];
  const float* b1v  = (const float*)d_in[3];
  const float* W2   = (const float*)d_in[4];
  const float* P2   = (const float*)d_in[5];
  const float* b2   = (const float*)d_in[6];
  float* out = (float*)d_out;

  const size_t BITS_BYTES  = (size_t)BSZ * T1 * 10 * sizeof(u32);   // 261,120
  const size_t K1BF_BYTES  = (size_t)5 * NC32 * KFRAG_U * 2;        // 14,950,400
  const size_t PBUF_BYTES  = (size_t)2 * 5 * 128 * 3264 * 4;        // 16,711,680
  const size_t NEED_S = PBUF_BYTES + K1BF_BYTES;                    // ~31.7 MB
  const size_t K1_OFF_M = 262144;
  const size_t NEED_M = K1_OFF_M + K1BF_BYTES;                      // ~15.2 MB

  if (ws_size >= NEED_S) {
    float* pbuf = (float*)d_ws;
    u16* K1bf   = (u16*)((char*)d_ws + PBUF_BYTES);
    snn_prepm<<<dim3(NC32, 5), 256, 0, stream>>>(W1, P1, K1bf);
    snn_l1s<<<1280, 256, 0, stream>>>(data, K1bf, pbuf);
    snn_l2m<<<BSZ, 256, 0, stream>>>(pbuf, b1v, W2, P2, b2, out);
  } else if (ws_size >= NEED_M) {
    u32* gbits = (u32*)d_ws;
    u16* K1bf  = (u16*)((char*)d_ws + K1_OFF_M);
    snn_prepm<<<dim3(NC32, 5), 256, 0, stream>>>(W1, P1, K1bf);
    snn_l1m<<<640, 256, 0, stream>>>(data, K1bf, b1v, gbits);
    snn_l2k<<<BSZ, 256, 0, stream>>>(gbits, W2, P2, b2, out);
  } else if (ws_size >= BITS_BYTES) {
    u32* gbits = (u32*)d_ws;
    snn_l1<<<dim3(5, BSZ), 256, 0, stream>>>(data, W1, P1, b1v, gbits);
    snn_l2k<<<BSZ, 256, 0, stream>>>(gbits, W2, P2, b2, out);
  } else {
    snn_mono<<<BSZ, 256, 0, stream>>>(data, W1, P1, b1v, W2, P2, b2, out);
  }
}

// Round 10
// 392.330 us; speedup vs baseline: 2.5098x; 1.0472x over previous
//
#include <hip/hip_runtime.h>

// Problem constants
#define BSZ  128
#define TT   50
#define CIN  2312
#define HID  300
#define NOUT 10
#define KS   5
#define T1   51          // (TT+5) - KS + 1
#define T2   52          // (T1+5) - KS + 1

#define NC32 73          // ceil(CIN/32) K-chunks of 32
#define KFRAG_U 20480    // u16 units per (ow,chunk): 5k * 4nt * 2h * 512

typedef unsigned int u32;
typedef unsigned short u16;
typedef __attribute__((ext_vector_type(8))) short s16x8;   // 8 bf16 (4 VGPRs)
typedef __attribute__((ext_vector_type(4))) float f32x4;   // MFMA C/D

// exp(-k^2/8) constants, k=1..4 (fp32)
#define EK1f 0.88249690258459546f
#define EK2f 0.60653065971263342f
#define EK3f 0.32465246735834974f
#define EK4f 0.13533528323661270f

static __device__ __forceinline__ u16 bfhi(float x) {
  u32 u = __float_as_uint(x);
  return (u16)((u + 0x7fffu + ((u >> 16) & 1u)) >> 16);   // RNE bf16
}
static __device__ __forceinline__ float bf2f(u16 h) {
  return __uint_as_float(((u32)h) << 16);
}

// ===========================================================================
// prep: synthesize gauss kernel once, split into bf16 hi/lo, in exact MFMA
// B-fragment order: [ow][chunk][k][nt][h][lane][8] (frag = 64 lanes x 16 B).
// ===========================================================================
__global__ __launch_bounds__(256) void snn_prepm(
    const float* __restrict__ W1, const float* __restrict__ P1,
    u16* __restrict__ K1bf)
{
  const int c  = blockIdx.x;          // 0..72
  const int ow = blockIdx.y;          // 0..4
  const int tid = threadIdx.x;
  const int nt = tid >> 6, ll = tid & 63;
  const int g = ll >> 4, lr = ll & 15;
  const int o  = ow * 64 + nt * 16 + lr;
  const int ib = c * 32 + g * 8;

  s16x8 hv[5], lv[5];
#pragma unroll
  for (int k = 0; k < 5; ++k)
#pragma unroll
    for (int j = 0; j < 8; ++j) { hv[k][j] = 0; lv[k][j] = 0; }

  if (o < HID) {
    const float* wrow = W1 + (size_t)o * CIN;
    const float* prow = P1 + (size_t)o * CIN;
#pragma unroll
    for (int j = 0; j < 8; ++j) {
      const int i = ib + j;
      if (i < CIN) {
        const float w1 = wrow[i], p1 = prow[i];
        const float cc = p1 + 2.0f;
        const float E0 = __expf(-0.125f * cc * cc);
        const float U  = __expf(0.25f * cc);
        const float u2 = U * U;
        const float e0 = E0;
        const float e1 = E0 * U * EK1f;
        const float e2 = E0 * u2 * EK2f;
        const float e3 = E0 * (u2 * U) * EK3f;
        const float e4 = E0 * (u2 * u2) * EK4f;
        const float inv = 1.0f / (((((e0 + e1) + e2) + e3) + e4) + 1e-7f);
        const float vk[5] = { w1 * (e0 * inv), w1 * (e1 * inv),
                              w1 * (e2 * inv), w1 * (e3 * inv),
                              w1 * (e4 * inv) };
#pragma unroll
        for (int k = 0; k < 5; ++k) {
          const u16 h = bfhi(vk[k]);
          const u16 lo = bfhi(vk[k] - bf2f(h));
          hv[k][j] = (short)h; lv[k][j] = (short)lo;
        }
      }
    }
  }
  u16* base = K1bf + ((size_t)ow * NC32 + c) * KFRAG_U + nt * 1024 + ll * 8;
#pragma unroll
  for (int k = 0; k < 5; ++k) {
    *(s16x8*)(base + k * 4096)       = hv[k];
    *(s16x8*)(base + k * 4096 + 512) = lv[k];
  }
}

// ===========================================================================
// Layer-1 split-K MFMA kernel, v2: BATCH-PAIRED.
// 640 blocks: (ow, s, bp) — each block computes TWO batches (b=2bp, 2bp+1)
// of one 64t x 64o tile over chunks [c_lo,c_hi). Waves (wb, wc): wave owns
// all 64 t rows of batch wb x 32 cols (ntg = 2wc, 2wc+1).
//   -> B frags shared per-wc only: per-batch B L2 traffic HALVES vs r9's
//      2x2 grid (3.74 -> 1.87 GB, the 108 us co-limiter -> 54).
//   -> grid 640 <= capacity (3 blocks/CU by LDS) -> all resident, NO TAIL
//      (r9: 1280 blocks vs 1024 capacity -> 256-block tail at 1 blk/CU).
// fp32 accumulation through the MFMA C chain (fp64 accd dropped: -32 VGPR,
// -promote pass; ~550 fp32 roundings -> ~1.4e-6 rel, below the 4e-6
// bf16-split noise already tolerated at absmax 0.0078).
// B loads just-in-time per tap (compiler pipelines; ~10 waves/CU TLP covers
// L2 latency). A: two 68-slot windows (one per batch), hi/lo bf16, double-
// buffered; natural stride-80B banking (r6 lesson: no xor).
// LDS: 2 bufs x 2 batches x (hi 2720 + lo 2720) u16 = 43520 B.
// pbuf layout identical to r9 -> l2m unchanged.
// ===========================================================================
__global__ __launch_bounds__(256, 2) void snn_l1s(
    const float* __restrict__ data, const u16* __restrict__ K1bf,
    float* __restrict__ pbuf)
{
  __shared__ __align__(16) u16 A16[21760];   // 43520 B

  const int tid = threadIdx.x;
  const int bid = blockIdx.x;
  const int g  = bid & 7;            // XCD
  const int u  = bid >> 3;           // 0..79
  const int x  = g * 80 + u;         // 0..639 (ow-major per XCD)
  const int ow = x >> 7;             // 0..4
  const int rem = x & 127;
  const int s  = rem >> 6;           // K-half
  const int bp = rem & 63;           // batch pair
  const int b0 = 2 * bp;

  const int c_lo = s ? 37 : 0;
  const int c_hi = s ? 73 : 37;

  const int w  = tid >> 6, l = tid & 63;
  const int lr = l & 15, lg = l >> 4;
  const int wb = w >> 1, wc = w & 1;           // batch-sub, col-half
  const int ntg0 = wc * 2, ntg1 = wc * 2 + 1;

  const u16* kbn = K1bf + (size_t)ow * NC32 * KFRAG_U + l * 8;

  // A staging thread mapping: slot s1 (0..63), i-group j4 (0..3), 2 batches
  const int s1 = tid >> 2;
  const int j4 = tid & 3;
  const int tp = s1 - 5;
  const bool avld = (tp >= 0) && (tp < TT);
  const float* aptrA = data + (size_t)b0 * (TT * CIN)
                       + (size_t)(avld ? tp : 0) * CIN + j4 * 8;
  const float* aptrB = aptrA + (size_t)(TT * CIN);   // batch b0+1

  // zero pad rows 64..67 (tap overhang): 2 bufs x 2 batches x hi/lo
  if (tid < 160) {
    s16x8 z;
#pragma unroll
    for (int j = 0; j < 8; ++j) z[j] = 0;
    const int r = tid / 20, off = (tid % 20) * 8;
    *(s16x8*)(A16 + (r >> 2) * 10880 + ((r >> 1) & 1) * 5440
              + (r & 1) * 2720 + 2560 + off) = z;
  }

#define LOADA(CC)                                                             \
  {                                                                           \
    const bool iv_ = avld && (((CC) < 72) || (j4 == 0));                      \
    const float* pa_ = aptrA + (size_t)(CC) * 32;                             \
    const float* pb_ = aptrB + (size_t)(CC) * 32;                             \
    raA0 = iv_ ? *(const float4*)(pa_)     : make_float4(0.f, 0.f, 0.f, 0.f); \
    raA1 = iv_ ? *(const float4*)(pa_ + 4) : make_float4(0.f, 0.f, 0.f, 0.f); \
    raB0 = iv_ ? *(const float4*)(pb_)     : make_float4(0.f, 0.f, 0.f, 0.f); \
    raB1 = iv_ ? *(const float4*)(pb_ + 4) : make_float4(0.f, 0.f, 0.f, 0.f); \
  }

#define STAGE_A(CC)                                                           \
  {                                                                           \
    u16* bn_ = A16 + ((CC) & 1) * 10880;                                      \
    const int woff_ = s1 * 40 + j4 * 8;                                       \
    {                                                                         \
      const float f_[8] = { raA0.x, raA0.y, raA0.z, raA0.w,                   \
                            raA1.x, raA1.y, raA1.z, raA1.w };                 \
      s16x8 hv_, lv_;                                                         \
      _Pragma("unroll")                                                       \
      for (int j = 0; j < 8; ++j) {                                           \
        const u16 h_ = bfhi(f_[j]);                                           \
        hv_[j] = (short)h_;                                                   \
        lv_[j] = (short)bfhi(f_[j] - bf2f(h_));                               \
      }                                                                       \
      *(s16x8*)(bn_ + woff_) = hv_;                                           \
      *(s16x8*)(bn_ + 2720 + woff_) = lv_;                                    \
    }                                                                         \
    {                                                                         \
      const float f_[8] = { raB0.x, raB0.y, raB0.z, raB0.w,                   \
                            raB1.x, raB1.y, raB1.z, raB1.w };                 \
      s16x8 hv_, lv_;                                                         \
      _Pragma("unroll")                                                       \
      for (int j = 0; j < 8; ++j) {                                           \
        const u16 h_ = bfhi(f_[j]);                                           \
        hv_[j] = (short)h_;                                                   \
        lv_[j] = (short)bfhi(f_[j] - bf2f(h_));                               \
      }                                                                       \
      *(s16x8*)(bn_ + 5440 + woff_) = hv_;                                    \
      *(s16x8*)(bn_ + 5440 + 2720 + woff_) = lv_;                             \
    }                                                                         \
  }

  // fp32 accumulators: wave's 64t x 32o = 4 m-frags x 2 n-frags
  f32x4 accf[4][2];
#pragma unroll
  for (int m = 0; m < 4; ++m)
#pragma unroll
    for (int n = 0; n < 2; ++n)
#pragma unroll
      for (int q = 0; q < 4; ++q) accf[m][n][q] = 0.f;

  // ---- prologue: stage chunk c_lo; prefetch A regs <- c_lo+1 ----
  float4 raA0, raA1, raB0, raB1;
  LOADA(c_lo);
  STAGE_A(c_lo);
  LOADA(c_lo + 1);
  __syncthreads();

  // ---- main loop: per-chunk barrier (r5/r9 proven schedule) ----
  for (int c = c_lo; c < c_hi; ++c) {
    if (c + 1 < c_hi) {
      STAGE_A(c + 1);
      if (c + 2 < c_hi) LOADA(c + 2);
    }

    // compute chunk c: 5 taps x 4 m x 2 n x 3 terms; B just-in-time
    {
      const u16* cb_ = kbn + (size_t)c * KFRAG_U;
      const u16* aw_ = A16 + (c & 1) * 10880 + wb * 5440;
#pragma unroll
      for (int k = 0; k < 5; ++k) {
        const u16* tb_ = cb_ + k * 4096;
        const s16x8 bh0 = *(const s16x8*)(tb_ + ntg0 * 1024);
        const s16x8 bl0 = *(const s16x8*)(tb_ + ntg0 * 1024 + 512);
        const s16x8 bh1 = *(const s16x8*)(tb_ + ntg1 * 1024);
        const s16x8 bl1 = *(const s16x8*)(tb_ + ntg1 * 1024 + 512);
#pragma unroll
        for (int m = 0; m < 4; ++m) {
          const int ar_ = (16 * m + lr + k) * 40 + lg * 8;
          const s16x8 ah = *(const s16x8*)(aw_ + ar_);
          const s16x8 al = *(const s16x8*)(aw_ + 2720 + ar_);
          accf[m][0] = __builtin_amdgcn_mfma_f32_16x16x32_bf16(ah, bh0, accf[m][0], 0, 0, 0);
          accf[m][0] = __builtin_amdgcn_mfma_f32_16x16x32_bf16(al, bh0, accf[m][0], 0, 0, 0);
          accf[m][0] = __builtin_amdgcn_mfma_f32_16x16x32_bf16(ah, bl0, accf[m][0], 0, 0, 0);
          accf[m][1] = __builtin_amdgcn_mfma_f32_16x16x32_bf16(ah, bh1, accf[m][1], 0, 0, 0);
          accf[m][1] = __builtin_amdgcn_mfma_f32_16x16x32_bf16(al, bh1, accf[m][1], 0, 0, 0);
          accf[m][1] = __builtin_amdgcn_mfma_f32_16x16x32_bf16(ah, bl1, accf[m][1], 0, 0, 0);
        }
      }
    }
    __syncthreads();
  }
#undef LOADA
#undef STAGE_A

  // ---- store fp32 partial tile [51][64] for this wave's batch ----
  // C/D layout: col = lane&15, row = (lane>>4)*4 + reg
  float* pb = pbuf + (((size_t)s * 5 + ow) * 128 + (b0 + wb)) * 3264;
#pragma unroll
  for (int m = 0; m < 4; ++m)
#pragma unroll
    for (int n = 0; n < 2; ++n)
#pragma unroll
      for (int q = 0; q < 4; ++q) {
        const int t = 16 * m + lg * 4 + q;
        if (t < T1) pb[t * 64 + wc * 32 + n * 16 + lr] = accf[m][n][q];
      }
}

// ===========================================================================
// Fused layer-2: reduce split-K partials + LIF1 + ballot + conv2 + LIF2.
// 128 blocks (one per batch). smem floats: [0,15000) K2s [o][k][i],
// [15000,15510) lbits u32, [15510,16030) y2s [t2][o].
// ===========================================================================
__global__ __launch_bounds__(256) void snn_l2m(
    const float* __restrict__ pbuf, const float* __restrict__ b1v,
    const float* __restrict__ W2, const float* __restrict__ P2,
    const float* __restrict__ b2, float* __restrict__ out)
{
  __shared__ float smem[16030];
  const int b = blockIdx.x, tid = threadIdx.x;
  float* K2s = smem;
  u32* lbits = (u32*)(smem + 15000);
  float* y2s = smem + 15510;

  // ---- K2 synthesis (all 256 threads) ----
  for (int idx = tid; idx < NOUT * HID; idx += 256) {
    const int o = idx / HID, i = idx % HID;
    const float w = W2[idx], p = P2[idx];
    const float c = p + 2.0f;
    float e[KS], ssum = 0.f;
#pragma unroll
    for (int k = 0; k < KS; ++k) {
      const float d = ((float)k - c) * 0.5f;
      e[k] = __expf(-0.5f * d * d);
      ssum += e[k];
    }
    const float denom = ssum + 1e-7f;
#pragma unroll
    for (int k = 0; k < KS; ++k)
      K2s[(o * KS + k) * HID + i] = w * (e[k] / denom);
  }

  // ---- fused reduce + LIF1 + ballot: wave w handles ow = w (+4) ----
  {
    const int w = tid >> 6, l = tid & 63;
    for (int ow = w; ow < 5; ow += 4) {
      const int o = ow * 64 + l;
      const bool valid = o < HID;
      const double bias = valid ? (double)b1v[o] : 0.0;
      const float* p0 = pbuf + (((size_t)0 * 5 + ow) * 128 + b) * 3264 + l;
      const float* p1 = pbuf + (((size_t)1 * 5 + ow) * 128 + b) * 3264 + l;
      double mem = 0.0;
      for (int t = 0; t < T1; ++t) {
        const double x = (double)p0[t * 64] + (double)p1[t * 64] + bias;
        const double reset = (mem > 1.0) ? 1.0 : 0.0;
        mem = __dsub_rn(__dadd_rn(__dmul_rn(0.9, mem), x), reset);
        const unsigned long long mk = __ballot(valid && (mem > 1.0));
        if (l == 0)  lbits[t * 10 + 2 * ow]     = (u32)mk;
        if (l == 32) lbits[t * 10 + 2 * ow + 1] = (u32)(mk >> 32);
      }
    }
  }
  __syncthreads();                    // fences K2s + lbits

  // ---- conv2 ----
  for (int task = tid; task < T2 * NOUT; task += 256) {
    const int t2 = task / NOUT, o = task % NOUT;
    float acc = b2[o];
#pragma unroll
    for (int k = 0; k < KS; ++k) {
      const int tp = t2 + k - KS;
      if (tp < 0 || tp >= T1) continue;
      const float* kr = K2s + (o * KS + k) * HID;
      const u32* br = lbits + tp * 10;
      for (int i = 0; i < HID; ++i)
        acc = fmaf((float)((br[i >> 5] >> (i & 31)) & 1u), kr[i], acc);
    }
    y2s[task] = acc;
  }
  __syncthreads();

  // ---- LIF2 + output ----
  if (tid < NOUT) {
    float mem = 0.f;
    for (int t = 0; t < T2; ++t) {
      const float x = y2s[t * NOUT + tid];
      const float reset = (mem > 1.0f) ? 1.0f : 0.0f;
      mem = __fsub_rn(__fadd_rn(__fmul_rn(0.9f, mem), x), reset);
      out[(size_t)t * (BSZ * NOUT) + b * NOUT + tid] = (mem > 1.0f) ? 1.0f : 0.0f;
      out[(size_t)T2 * BSZ * NOUT + (size_t)t * (BSZ * NOUT) + b * NOUT + tid] = mem;
    }
  }
}

// ===========================================================================
// Fallback 1: round-5 proven l1m (full-K per block, gbits output) — used
// when workspace fits K1bf but not the split-K partial buffer.
// ===========================================================================
__global__ __launch_bounds__(256, 2) void snn_l1m(
    const float* __restrict__ data, const u16* __restrict__ K1bf,
    const float* __restrict__ b1v, u32* __restrict__ gbits)
{
  __shared__ double dsm[3264];         // 26112 B
  u16* A16 = (u16*)dsm;

  const int tid = threadIdx.x;
  const int bid = blockIdx.x;
  const int rnk = (bid & 7) * 80 + (bid >> 3);
  const int ow = rnk >> 7;
  const int b  = rnk & 127;

  const int w  = tid >> 6, l = tid & 63;
  const int lr = l & 15, lg = l >> 4;
  const int wr = w >> 1, wc = w & 1;
  const int abase_u = (32 * wr + lr) * 40 + lg * 8;

  const float* dbase = data + (size_t)b * (TT * CIN);
  const u16* kbn = K1bf + (size_t)ow * NC32 * KFRAG_U + l * 8;
  const int ntg0 = wc * 2, ntg1 = wc * 2 + 1;

  const int s1 = tid >> 2;
  const int j4 = tid & 3;
  const int tp = s1 - 5;
  const bool avld = (tp >= 0) && (tp < TT);
  const float* aptr = dbase + (size_t)(avld ? tp : 0) * CIN + j4 * 8;

  if (tid < 80) {
    s16x8 z;
#pragma unroll
    for (int j = 0; j < 8; ++j) z[j] = 0;
    const int rr = tid / 20, off = (tid % 20) * 8;
    *(s16x8*)(A16 + rr * 2720 + 2560 + off) = z;
  }

#define LOADA(CC)                                                             \
  {                                                                           \
    const bool iv_ = avld && (((CC) < 72) || (j4 == 0));                      \
    const float* pp_ = aptr + (size_t)(CC) * 32;                              \
    ra0 = iv_ ? *(const float4*)(pp_)     : make_float4(0.f, 0.f, 0.f, 0.f);  \
    ra1 = iv_ ? *(const float4*)(pp_ + 4) : make_float4(0.f, 0.f, 0.f, 0.f);  \
  }

#define STAGE_A(CC)                                                           \
  {                                                                           \
    const float f_[8] = { ra0.x, ra0.y, ra0.z, ra0.w,                         \
                          ra1.x, ra1.y, ra1.z, ra1.w };                       \
    s16x8 hv_, lv_;                                                           \
    _Pragma("unroll")                                                         \
    for (int j = 0; j < 8; ++j) {                                             \
      const u16 h_ = bfhi(f_[j]);                                             \
      hv_[j] = (short)h_;                                                     \
      lv_[j] = (short)bfhi(f_[j] - bf2f(h_));                                 \
    }                                                                         \
    u16* bn_ = A16 + ((CC) & 1) * 5440;                                       \
    const int woff_ = s1 * 40 + j4 * 8;                                       \
    *(s16x8*)(bn_ + woff_) = hv_;                                             \
    *(s16x8*)(bn_ + 2720 + woff_) = lv_;                                      \
  }

  s16x8 bh[5][2], bl[5][2];
#pragma unroll
  for (int k = 0; k < 5; ++k) {
    const u16* cb_ = kbn + k * 4096;
    bh[k][0] = *(const s16x8*)(cb_ + ntg0 * 1024);
    bh[k][1] = *(const s16x8*)(cb_ + ntg1 * 1024);
    bl[k][0] = *(const s16x8*)(cb_ + ntg0 * 1024 + 512);
    bl[k][1] = *(const s16x8*)(cb_ + ntg1 * 1024 + 512);
  }

  f32x4 accf[2][2];
  double accd[2][2][4];
#pragma unroll
  for (int m = 0; m < 2; ++m)
#pragma unroll
    for (int n = 0; n < 2; ++n)
#pragma unroll
      for (int q = 0; q < 4; ++q) { accf[m][n][q] = 0.f; accd[m][n][q] = 0.0; }

  float4 ra0, ra1;
  LOADA(0);
  STAGE_A(0);
  LOADA(1);
  __syncthreads();

  for (int c = 0; c < NC32; ++c) {
    if (c + 1 < NC32) {
      STAGE_A(c + 1);
      if (c + 2 < NC32) LOADA(c + 2);
    }
    {
      const u16* bc_ = A16 + (c & 1) * 5440;
      const int rc = c + 1;
#pragma unroll
      for (int k = 0; k < 5; ++k) {
        const s16x8 ah0 = *(const s16x8*)(bc_ + abase_u + k * 40);
        const s16x8 al0 = *(const s16x8*)(bc_ + 2720 + abase_u + k * 40);
        const s16x8 ah1 = *(const s16x8*)(bc_ + abase_u + (16 + k) * 40);
        const s16x8 al1 = *(const s16x8*)(bc_ + 2720 + abase_u + (16 + k) * 40);

        accf[0][0] = __builtin_amdgcn_mfma_f32_16x16x32_bf16(ah0, bh[k][0], accf[0][0], 0, 0, 0);
        accf[0][0] = __builtin_amdgcn_mfma_f32_16x16x32_bf16(al0, bh[k][0], accf[0][0], 0, 0, 0);
        accf[0][0] = __builtin_amdgcn_mfma_f32_16x16x32_bf16(ah0, bl[k][0], accf[0][0], 0, 0, 0);
        accf[0][1] = __builtin_amdgcn_mfma_f32_16x16x32_bf16(ah0, bh[k][1], accf[0][1], 0, 0, 0);
        accf[0][1] = __builtin_amdgcn_mfma_f32_16x16x32_bf16(al0, bh[k][1], accf[0][1], 0, 0, 0);
        accf[0][1] = __builtin_amdgcn_mfma_f32_16x16x32_bf16(ah0, bl[k][1], accf[0][1], 0, 0, 0);
        accf[1][0] = __builtin_amdgcn_mfma_f32_16x16x32_bf16(ah1, bh[k][0], accf[1][0], 0, 0, 0);
        accf[1][0] = __builtin_amdgcn_mfma_f32_16x16x32_bf16(al1, bh[k][0], accf[1][0], 0, 0, 0);
        accf[1][0] = __builtin_amdgcn_mfma_f32_16x16x32_bf16(ah1, bl[k][0], accf[1][0], 0, 0, 0);
        accf[1][1] = __builtin_amdgcn_mfma_f32_16x16x32_bf16(ah1, bh[k][1], accf[1][1], 0, 0, 0);
        accf[1][1] = __builtin_amdgcn_mfma_f32_16x16x32_bf16(al1, bh[k][1], accf[1][1], 0, 0, 0);
        accf[1][1] = __builtin_amdgcn_mfma_f32_16x16x32_bf16(ah1, bl[k][1], accf[1][1], 0, 0, 0);

        if (rc < NC32) {
          const u16* cb_ = kbn + (size_t)rc * KFRAG_U + k * 4096;
          bh[k][0] = *(const s16x8*)(cb_ + ntg0 * 1024);
          bh[k][1] = *(const s16x8*)(cb_ + ntg1 * 1024);
          bl[k][0] = *(const s16x8*)(cb_ + ntg0 * 1024 + 512);
          bl[k][1] = *(const s16x8*)(cb_ + ntg1 * 1024 + 512);
        }
      }
    }
#pragma unroll
    for (int m = 0; m < 2; ++m)
#pragma unroll
      for (int n = 0; n < 2; ++n)
#pragma unroll
        for (int q = 0; q < 4; ++q) {
          accd[m][n][q] += (double)accf[m][n][q];
          accf[m][n][q] = 0.f;
        }
    __syncthreads();
  }
#undef LOADA
#undef STAGE_A

  double* y1s = dsm;
#pragma unroll
  for (int m = 0; m < 2; ++m)
#pragma unroll
    for (int n = 0; n < 2; ++n)
#pragma unroll
      for (int q = 0; q < 4; ++q) {
        const int t = 32 * wr + 16 * m + lg * 4 + q;
        if (t < T1) y1s[t * 64 + 32 * wc + 16 * n + lr] = accd[m][n][q];
      }
  __syncthreads();

  if (tid < 64) {
    const int o = ow * 64 + tid;
    const bool valid = o < HID;
    const double bias = valid ? (double)b1v[o] : 0.0;
    u32* bits = gbits + (size_t)b * 510;
    double mem = 0.0;
    for (int t = 0; t < T1; ++t) {
      const double x = y1s[t * 64 + tid] + bias;
      const double reset = (mem > 1.0) ? 1.0 : 0.0;
      mem = __dsub_rn(__dadd_rn(__dmul_rn(0.9, mem), x), reset);
      const unsigned long long mk = __ballot(valid && (mem > 1.0));
      if (tid == 0)  bits[t * 10 + 2 * ow]     = (u32)mk;
      if (tid == 32) bits[t * 10 + 2 * ow + 1] = (u32)(mk >> 32);
    }
  }
}

// ===========================================================================
// Fallback 2: fp32 layer-1 (gauss in-kernel) — round-1/2 proven path.
// ===========================================================================
__device__ __forceinline__ void layer1_tile_g(
    int b, int ow, int tid,
    const float* __restrict__ data, const float* __restrict__ W1,
    const float* __restrict__ P1, const float* __restrict__ b1v,
    double* __restrict__ dsm, u32* __restrict__ bits)
{
  float* Bsf = (float*)dsm;
  float* As  = (float*)dsm + 2880;

  const int ty = tid >> 5;
  const int tx = tid & 31;
  const int r0 = ty << 3;
  const int c0 = tx << 1;

  const float* abase = data + (size_t)b * (TT * CIN);

  const int slot = tid >> 2;
  const int pair = tid & 3;
  const int tp   = slot - 5;

  const int isub = tid & 7;
  const int oA = tid >> 3;
  const int oB = oA + 32;
  const int boA = ow * 64 + oA;
  const int boB = ow * 64 + oB;
  const bool vB = boB < HID;

  double acc[8][2];
#pragma unroll
  for (int r = 0; r < 8; ++r) { acc[r][0] = 0.0; acc[r][1] = 0.0; }

  float2 aA = make_float2(0.f, 0.f);
  float wA = 0.f, pA = 0.f, wB = 0.f, pB = 0.f;
  if (tid < 220 && tp >= 0)
    aA = *(const float2*)(abase + (size_t)tp * CIN + 2 * pair);
  wA = W1[(size_t)boA * CIN + isub];
  pA = P1[(size_t)boA * CIN + isub];
  if (vB) {
    wB = W1[(size_t)boB * CIN + isub];
    pB = P1[(size_t)boB * CIN + isub];
  }

  for (int i0 = 0; i0 < CIN; i0 += 8) {
    if (tid < 220) {
      As[(2 * pair) * 80 + slot]     = aA.x;
      As[(2 * pair + 1) * 80 + slot] = aA.y;
    }
    {
      const float c  = pA + 2.0f;
      const float E0 = __expf(-0.125f * c * c);
      const float U  = __expf(0.25f * c);
      const float u2 = U * U;
      const float e0 = E0;
      const float e1 = E0 * U * EK1f;
      const float e2 = E0 * u2 * EK2f;
      const float e3 = E0 * (u2 * U) * EK3f;
      const float e4 = E0 * (u2 * u2) * EK4f;
      const float inv = 1.0f / (((((e0 + e1) + e2) + e3) + e4) + 1e-7f);
      float* bp = Bsf + isub * 72 + oA;
      bp[0]    = wA * (e0 * inv);
      bp[576]  = wA * (e1 * inv);
      bp[1152] = wA * (e2 * inv);
      bp[1728] = wA * (e3 * inv);
      bp[2304] = wA * (e4 * inv);
    }
    {
      const float c  = pB + 2.0f;
      const float E0 = __expf(-0.125f * c * c);
      const float U  = __expf(0.25f * c);
      const float u2 = U * U;
      const float e0 = E0;
      const float e1 = E0 * U * EK1f;
      const float e2 = E0 * u2 * EK2f;
      const float e3 = E0 * (u2 * U) * EK3f;
      const float e4 = E0 * (u2 * u2) * EK4f;
      const float inv = 1.0f / (((((e0 + e1) + e2) + e3) + e4) + 1e-7f);
      float* bp = Bsf + isub * 72 + oB;
      bp[0]    = wB * (e0 * inv);
      bp[576]  = wB * (e1 * inv);
      bp[1152] = wB * (e2 * inv);
      bp[1728] = wB * (e3 * inv);
      bp[2304] = wB * (e4 * inv);
    }
    __syncthreads();

    const int i0n = i0 + 8;
    if (i0n < CIN) {
      if (tid < 220 && tp >= 0)
        aA = *(const float2*)(abase + (size_t)tp * CIN + i0n + 2 * pair);
      wA = W1[(size_t)boA * CIN + i0n + isub];
      pA = P1[(size_t)boA * CIN + i0n + isub];
      if (vB) {
        wB = W1[(size_t)boB * CIN + i0n + isub];
        pB = P1[(size_t)boB * CIN + i0n + isub];
      }
    }

    float accf[8][2];
#pragma unroll
    for (int r = 0; r < 8; ++r) { accf[r][0] = 0.f; accf[r][1] = 0.f; }
#pragma unroll
    for (int kk = 0; kk < 8; ++kk) {
      const float* ap = &As[kk * 80 + r0];
      const float4 a0 = *(const float4*)(ap);
      const float4 a1 = *(const float4*)(ap + 4);
      const float4 a2 = *(const float4*)(ap + 8);
      float av[12];
      av[0] = a0.x; av[1] = a0.y; av[2]  = a0.z; av[3]  = a0.w;
      av[4] = a1.x; av[5] = a1.y; av[6]  = a1.z; av[7]  = a1.w;
      av[8] = a2.x; av[9] = a2.y; av[10] = a2.z; av[11] = a2.w;
      float bv[KS][2];
#pragma unroll
      for (int k = 0; k < KS; ++k) {
        const float2 bb = *(const float2*)&Bsf[(k * 8 + kk) * 72 + c0];
        bv[k][0] = bb.x; bv[k][1] = bb.y;
      }
#pragma unroll
      for (int k = 0; k < KS; ++k)
#pragma unroll
        for (int r = 0; r < 8; ++r) {
          accf[r][0] = fmaf(av[r + k], bv[k][0], accf[r][0]);
          accf[r][1] = fmaf(av[r + k], bv[k][1], accf[r][1]);
        }
    }
#pragma unroll
    for (int r = 0; r < 8; ++r) {
      acc[r][0] += (double)accf[r][0];
      acc[r][1] += (double)accf[r][1];
    }
    __syncthreads();
  }

  double* y1s = dsm;
#pragma unroll
  for (int r = 0; r < 8; ++r) {
    const int t = r0 + r;
    if (t < T1) {
      y1s[t * 64 + c0]     = acc[r][0];
      y1s[t * 64 + c0 + 1] = acc[r][1];
    }
  }
  __syncthreads();

  if (tid < 64) {
    const int o = ow * 64 + tid;
    const bool valid = o < HID;
    const double bias = valid ? (double)b1v[o] : 0.0;
    double mem = 0.0;
    for (int t = 0; t < T1; ++t) {
      const double x = y1s[t * 64 + tid] + bias;
      const double reset = (mem > 1.0) ? 1.0 : 0.0;
      mem = __dsub_rn(__dadd_rn(__dmul_rn(0.9, mem), x), reset);
      const unsigned long long mk = __ballot(valid && (mem > 1.0));
      if (tid == 0)  bits[t * 10 + 2 * ow]     = (u32)mk;
      if (tid == 32) bits[t * 10 + 2 * ow + 1] = (u32)(mk >> 32);
    }
  }
  __syncthreads();
}

// ---------------------------------------------------------------------------
// Layer-2 conv + LIF2 (fp32), gbits variant (fallback paths).
// ---------------------------------------------------------------------------
__device__ __forceinline__ void layer2_lif2(
    int b, int tid, float* smem,
    const float* __restrict__ W2, const float* __restrict__ P2,
    const float* __restrict__ b2, float* __restrict__ out)
{
  float* K2s = smem;
  const u32* lbits = (const u32*)(smem + 15000);
  float* y2s = smem + 15510;

  for (int idx = tid; idx < NOUT * HID; idx += 256) {
    const int o = idx / HID, i = idx % HID;
    const float w = W2[idx], p = P2[idx];
    const float c = p + 2.0f;
    float e[KS], s = 0.f;
#pragma unroll
    for (int k = 0; k < KS; ++k) {
      const float d = ((float)k - c) * 0.5f;
      e[k] = __expf(-0.5f * d * d);
      s += e[k];
    }
    const float denom = s + 1e-7f;
#pragma unroll
    for (int k = 0; k < KS; ++k)
      K2s[(o * KS + k) * HID + i] = w * (e[k] / denom);
  }
  __syncthreads();

  for (int task = tid; task < T2 * NOUT; task += 256) {
    const int t2 = task / NOUT, o = task % NOUT;
    float acc = b2[o];
#pragma unroll
    for (int k = 0; k < KS; ++k) {
      const int tp = t2 + k - KS;
      if (tp < 0 || tp >= T1) continue;
      const float* kr = K2s + (o * KS + k) * HID;
      const u32* br = lbits + tp * 10;
      for (int i = 0; i < HID; ++i)
        acc = fmaf((float)((br[i >> 5] >> (i & 31)) & 1u), kr[i], acc);
    }
    y2s[task] = acc;
  }
  __syncthreads();

  if (tid < NOUT) {
    float mem = 0.f;
    for (int t = 0; t < T2; ++t) {
      const float x = y2s[t * NOUT + tid];
      const float reset = (mem > 1.0f) ? 1.0f : 0.0f;
      mem = __fsub_rn(__fadd_rn(__fmul_rn(0.9f, mem), x), reset);
      out[(size_t)t * (BSZ * NOUT) + b * NOUT + tid] = (mem > 1.0f) ? 1.0f : 0.0f;
      out[(size_t)T2 * BSZ * NOUT + (size_t)t * (BSZ * NOUT) + b * NOUT + tid] = mem;
    }
  }
}

// ---------------- fallback kernels ------------------------------------------
__global__ __launch_bounds__(256) void snn_l1(
    const float* __restrict__ data, const float* __restrict__ W1,
    const float* __restrict__ P1, const float* __restrict__ b1v,
    u32* __restrict__ gbits)
{
  __shared__ double dsm[3264];
  const int ow = blockIdx.x, b = blockIdx.y;
  layer1_tile_g(b, ow, threadIdx.x, data, W1, P1, b1v, dsm,
                gbits + (size_t)b * 510);
}

__global__ __launch_bounds__(256) void snn_l2k(
    const u32* __restrict__ gbits,
    const float* __restrict__ W2, const float* __restrict__ P2,
    const float* __restrict__ b2, float* __restrict__ out)
{
  __shared__ float smem[16030];
  const int b = blockIdx.x, tid = threadIdx.x;
  u32* lbits = (u32*)(smem + 15000);
  for (int i = tid; i < 510; i += 256) lbits[i] = gbits[(size_t)b * 510 + i];
  layer2_lif2(b, tid, smem, W2, P2, b2, out);
}

__global__ __launch_bounds__(256) void snn_mono(
    const float* __restrict__ data, const float* __restrict__ W1,
    const float* __restrict__ P1, const float* __restrict__ b1v,
    const float* __restrict__ W2, const float* __restrict__ P2,
    const float* __restrict__ b2, float* __restrict__ out)
{
  __shared__ double dsm[8015];
  const int b = blockIdx.x, tid = threadIdx.x;
  u32* lbits = (u32*)((float*)dsm + 15000);
  for (int ow = 0; ow < 5; ++ow)
    layer1_tile_g(b, ow, tid, data, W1, P1, b1v, dsm, lbits);
  layer2_lif2(b, tid, (float*)dsm, W2, P2, b2, out);
}

// ---------------- launcher --------------------------------------------------
extern "C" void kernel_launch(void* const* d_in, const int* in_sizes, int n_in,
                              void* d_out, int out_size, void* d_ws, size_t ws_size,
                              hipStream_t stream) {
  const float* data = (const float*)d_in[0];
  const float* W1   = (const float*)d_in[1];
  const float* P1   = (const float*)d_in[2];
  const float* b1v  = (const float*)d_in[3];
  const float* W2   = (const float*)d_in[4];
  const float* P2   = (const float*)d_in[5];
  const float* b2   = (const float*)d_in[6];
  float* out = (float*)d_out;

  const size_t BITS_BYTES  = (size_t)BSZ * T1 * 10 * sizeof(u32);   // 261,120
  const size_t K1BF_BYTES  = (size_t)5 * NC32 * KFRAG_U * 2;        // 14,950,400
  const size_t PBUF_BYTES  = (size_t)2 * 5 * 128 * 3264 * 4;        // 16,711,680
  const size_t NEED_S = PBUF_BYTES + K1BF_BYTES;                    // ~31.7 MB
  const size_t K1_OFF_M = 262144;
  const size_t NEED_M = K1_OFF_M + K1BF_BYTES;                      // ~15.2 MB

  if (ws_size >= NEED_S) {
    float* pbuf = (float*)d_ws;
    u16* K1bf   = (u16*)((char*)d_ws + PBUF_BYTES);
    snn_prepm<<<dim3(NC32, 5), 256, 0, stream>>>(W1, P1, K1bf);
    snn_l1s<<<640, 256, 0, stream>>>(data, K1bf, pbuf);
    snn_l2m<<<BSZ, 256, 0, stream>>>(pbuf, b1v, W2, P2, b2, out);
  } else if (ws_size >= NEED_M) {
    u32* gbits = (u32*)d_ws;
    u16* K1bf  = (u16*)((char*)d_ws + K1_OFF_M);
    snn_prepm<<<dim3(NC32, 5), 256, 0, stream>>>(W1, P1, K1bf);
    snn_l1m<<<640, 256, 0, stream>>>(data, K1bf, b1v, gbits);
    snn_l2k<<<BSZ, 256, 0, stream>>>(gbits, W2, P2, b2, out);
  } else if (ws_size >= BITS_BYTES) {
    u32* gbits = (u32*)d_ws;
    snn_l1<<<dim3(5, BSZ), 256, 0, stream>>>(data, W1, P1, b1v, gbits);
    snn_l2k<<<BSZ, 256, 0, stream>>>(gbits, W2, P2, b2, out);
  } else {
    snn_mono<<<BSZ, 256, 0, stream>>>(data, W1, P1, b1v, W2, P2, b2, out);
  }
}